// Round 1
// baseline (1786.350 us; speedup 1.0000x reference)
//
#include <hip/hip_runtime.h>
#include <math.h>

// Problem constants: B=32, T=128, R=9, D=512. 64 pairs (32 pos + 32 neg).
#define BTRD (128*9*512)

// ---------------------------------------------------------------------------
// Stage A: sim[pb, i, j] = mean_o max_p dot(Q[b,i,o,:], T[b,j,p,:]), masked.
// Block: 16 i x 16 j, one (i,j) per thread, acc[9][9] in registers.
// ---------------------------------------------------------------------------
__global__ __launch_bounds__(256, 2) void sim_kernel(
    const float* __restrict__ A, const float* __restrict__ P, const float* __restrict__ Nn,
    const float* __restrict__ qm, const float* __restrict__ pm, const float* __restrict__ nm,
    float* __restrict__ simout)
{
  const int RS = 36;  // 32 + 4 pad words; row stride mod 32 == 4 -> 2-way (free)
  int pb = blockIdx.z;
  int b = pb & 31, g = pb >> 5;
  const float* Q = A + (size_t)b * BTRD;
  const float* T = (g ? Nn : P) + (size_t)b * BTRD;
  int i0 = blockIdx.y * 16, j0 = blockIdx.x * 16;

  __shared__ float q_s[144 * 36];
  __shared__ float t_s[144 * 36];

  int tid = threadIdx.x;
  int ti = tid & 15, tj = tid >> 4;

  float acc[9][9];
#pragma unroll
  for (int o = 0; o < 9; o++)
#pragma unroll
    for (int p = 0; p < 9; p++) acc[o][p] = 0.f;

  for (int k0 = 0; k0 < 512; k0 += 32) {
    // stage 144 rows x 32 floats for q and t tiles (float4 coalesced)
    for (int r = tid; r < 1152; r += 256) {
      int row = r >> 3, c4 = r & 7;
      int ii = row / 9, o = row - ii * 9;
      float4 qv = *(const float4*)(Q + (((size_t)(i0 + ii) * 9 + o) << 9) + k0 + (c4 << 2));
      *(float4*)&q_s[row * RS + (c4 << 2)] = qv;
      float4 tv = *(const float4*)(T + (((size_t)(j0 + ii) * 9 + o) << 9) + k0 + (c4 << 2));
      *(float4*)&t_s[row * RS + (c4 << 2)] = tv;
    }
    __syncthreads();

    for (int kk = 0; kk < 32; kk += 4) {
      float4 tv[9];
#pragma unroll
      for (int p = 0; p < 9; p++) tv[p] = *(const float4*)&t_s[(tj * 9 + p) * RS + kk];
#pragma unroll
      for (int o = 0; o < 9; o++) {
        float4 qv = *(const float4*)&q_s[(ti * 9 + o) * RS + kk];
#pragma unroll
        for (int p = 0; p < 9; p++) {
          acc[o][p] = fmaf(qv.x, tv[p].x, acc[o][p]);
          acc[o][p] = fmaf(qv.y, tv[p].y, acc[o][p]);
          acc[o][p] = fmaf(qv.z, tv[p].z, acc[o][p]);
          acc[o][p] = fmaf(qv.w, tv[p].w, acc[o][p]);
        }
      }
    }
    __syncthreads();
  }

  float s = 0.f;
#pragma unroll
  for (int o = 0; o < 9; o++) {
    float mx = acc[o][0];
#pragma unroll
    for (int p = 1; p < 9; p++) mx = fmaxf(mx, acc[o][p]);
    s += mx;
  }
  s = s / 9.0f;

  int i = i0 + ti, j = j0 + tj;
  float m = qm[b * 128 + i] * ((g ? nm : pm)[b * 128 + j]);
  simout[((size_t)pb * 128 + i) * 128 + j] = (m > 0.f) ? s : 0.f;
}

// ---------------------------------------------------------------------------
// Stage B1: conv1(3x3, 1->32) + bias + relu + maxpool2. One thread per
// (b2, pooled y, pooled x), all 32 oc. relu(max4(c)+b) == maxpool(relu(c+b)).
// ---------------------------------------------------------------------------
__global__ __launch_bounds__(256) void conv1_kernel(
    const float* __restrict__ sim, const float* __restrict__ w1,
    const float* __restrict__ b1, float* __restrict__ x1)
{
  __shared__ float w_s[288];
  __shared__ float b_s[32];
  int tid = threadIdx.x;
  for (int e = tid; e < 288; e += 256) w_s[e] = w1[e];
  if (tid < 32) b_s[tid] = b1[tid];
  __syncthreads();

  int idx = blockIdx.x * 256 + tid;       // 64*64*64 total
  int x = idx & 63, y = (idx >> 6) & 63, b2 = idx >> 12;
  const float* sb = sim + (size_t)b2 * 16384;

  float patch[4][4];
#pragma unroll
  for (int r = 0; r < 4; r++) {
    int Y = 2 * y - 1 + r;
#pragma unroll
    for (int c = 0; c < 4; c++) {
      int X = 2 * x - 1 + c;
      patch[r][c] = (Y >= 0 && Y < 128 && X >= 0 && X < 128) ? sb[Y * 128 + X] : 0.f;
    }
  }

  for (int oc = 0; oc < 32; oc++) {
    float c00 = 0, c01 = 0, c10 = 0, c11 = 0;
#pragma unroll
    for (int tap = 0; tap < 9; tap++) {
      int dy = tap / 3, dx = tap - dy * 3;
      float w = w_s[oc * 9 + tap];
      c00 = fmaf(w, patch[dy][dx], c00);
      c01 = fmaf(w, patch[dy][dx + 1], c01);
      c10 = fmaf(w, patch[dy + 1][dx], c10);
      c11 = fmaf(w, patch[dy + 1][dx + 1], c11);
    }
    float v = fmaxf(fmaxf(c00, c01), fmaxf(c10, c11)) + b_s[oc];
    v = fmaxf(v, 0.f);
    x1[(((size_t)b2 * 32 + oc) * 64 + y) * 64 + x] = v;
  }
}

// ---------------------------------------------------------------------------
// Stage B2: conv2(3x3, 32->64) + bias + relu + maxpool2.
// Block: (b2, 16x16 conv tile). Thread: 16 oc x 2x2 pixel quad (pool window).
// ---------------------------------------------------------------------------
__global__ __launch_bounds__(256, 2) void conv2_kernel(
    const float* __restrict__ x1, const float* __restrict__ w2,
    const float* __restrict__ bb, float* __restrict__ x2)
{
  int b2 = blockIdx.y;
  int t = blockIdx.x;                 // 0..15
  int ty0 = (t >> 2) * 16, tx0 = (t & 3) * 16;

  __shared__ float in_s[8 * 18 * 19]; // [icl][row][col], col stride 19
  __shared__ float w_s[8 * 9 * 64];   // [(icl*9+tap)*64 + oc]

  int tid = threadIdx.x;
  int ocg = tid >> 6;                 // 0..3 (16 oc each)
  int qid = tid & 63;
  int qy = qid >> 3, qx = qid & 7;    // quad at (2qy, 2qx) in 16x16 tile

  float acc[16][4];
#pragma unroll
  for (int u = 0; u < 16; u++) { acc[u][0] = 0; acc[u][1] = 0; acc[u][2] = 0; acc[u][3] = 0; }

  for (int ic0 = 0; ic0 < 32; ic0 += 8) {
    for (int e = tid; e < 8 * 18 * 18; e += 256) {
      int icl = e / 324; int rem = e - icl * 324;
      int row = rem / 18; int col = rem - row * 18;
      int gy = ty0 - 1 + row, gx = tx0 - 1 + col;
      float v = 0.f;
      if (gy >= 0 && gy < 64 && gx >= 0 && gx < 64)
        v = x1[(((size_t)b2 * 32 + ic0 + icl) * 64 + gy) * 64 + gx];
      in_s[icl * 342 + row * 19 + col] = v;
    }
    for (int e = tid; e < 8 * 9 * 64; e += 256) {
      int oc = e & 63, r = e >> 6;
      int icl = r / 9, tap = r - icl * 9;
      w_s[e] = w2[(oc * 32 + ic0 + icl) * 9 + tap];
    }
    __syncthreads();

    for (int icl = 0; icl < 8; ++icl) {
#pragma unroll
      for (int tap = 0; tap < 9; ++tap) {
        int dy = tap / 3, dx = tap - dy * 3;
        int ib = icl * 342 + (2 * qy + dy) * 19 + 2 * qx + dx;
        float iv00 = in_s[ib], iv01 = in_s[ib + 1];
        float iv10 = in_s[ib + 19], iv11 = in_s[ib + 20];
        const float4* w4 = (const float4*)&w_s[(icl * 9 + tap) * 64 + ocg * 16];
        float wv[16];
#pragma unroll
        for (int u4 = 0; u4 < 4; u4++) {
          float4 w = w4[u4];
          wv[u4 * 4 + 0] = w.x; wv[u4 * 4 + 1] = w.y; wv[u4 * 4 + 2] = w.z; wv[u4 * 4 + 3] = w.w;
        }
#pragma unroll
        for (int u = 0; u < 16; u++) {
          acc[u][0] = fmaf(wv[u], iv00, acc[u][0]);
          acc[u][1] = fmaf(wv[u], iv01, acc[u][1]);
          acc[u][2] = fmaf(wv[u], iv10, acc[u][2]);
          acc[u][3] = fmaf(wv[u], iv11, acc[u][3]);
        }
      }
    }
    __syncthreads();
  }

  int py = (ty0 >> 1) + qy, px = (tx0 >> 1) + qx;
#pragma unroll
  for (int u = 0; u < 16; u++) {
    int oc = ocg * 16 + u;
    float v = fmaxf(fmaxf(acc[u][0], acc[u][1]), fmaxf(acc[u][2], acc[u][3])) + bb[oc];
    v = fmaxf(v, 0.f);
    x2[(((size_t)b2 * 64 + oc) * 32 + py) * 32 + px] = v;
  }
}

// ---------------------------------------------------------------------------
// Stage B3: conv3(3x3, 64->128) + bias + relu, fused with convf(1x1, 128->1)
// + bf. Block: (b2, 16x8 conv tile). Thread: 16 oc x 2x2 quad. Cross-ocg
// reduction in LDS, writes s_head (64,32,32) directly (x3 never materialized).
// ---------------------------------------------------------------------------
__global__ __launch_bounds__(256, 2) void conv3_kernel(
    const float* __restrict__ x2, const float* __restrict__ w3,
    const float* __restrict__ b3, const float* __restrict__ wf,
    const float* __restrict__ bf, float* __restrict__ shead)
{
  int b2 = blockIdx.y;
  int t = blockIdx.x;                 // 0..7
  int ty0 = (t >> 1) * 8, tx0 = (t & 1) * 16;

  __shared__ float in_s[8 * 10 * 19];
  __shared__ float w_s[8 * 9 * 128];
  __shared__ float ps[8 * 128];

  int tid = threadIdx.x;
  int ocg = tid >> 5;                 // 0..7 (16 oc each)
  int qid = tid & 31;
  int qy = qid >> 3, qx = qid & 7;    // quads: 4y x 8x -> 8x16 pixels

  float acc[16][4];
#pragma unroll
  for (int u = 0; u < 16; u++) { acc[u][0] = 0; acc[u][1] = 0; acc[u][2] = 0; acc[u][3] = 0; }

  for (int ic0 = 0; ic0 < 64; ic0 += 8) {
    for (int e = tid; e < 8 * 10 * 18; e += 256) {
      int icl = e / 180; int rem = e - icl * 180;
      int row = rem / 18; int col = rem - row * 18;
      int gy = ty0 - 1 + row, gx = tx0 - 1 + col;
      float v = 0.f;
      if (gy >= 0 && gy < 32 && gx >= 0 && gx < 32)
        v = x2[(((size_t)b2 * 64 + ic0 + icl) * 32 + gy) * 32 + gx];
      in_s[icl * 190 + row * 19 + col] = v;
    }
    for (int e = tid; e < 8 * 9 * 128; e += 256) {
      int oc = e & 127, r = e >> 7;
      int icl = r / 9, tap = r - icl * 9;
      w_s[e] = w3[(oc * 64 + ic0 + icl) * 9 + tap];
    }
    __syncthreads();

    for (int icl = 0; icl < 8; ++icl) {
#pragma unroll
      for (int tap = 0; tap < 9; ++tap) {
        int dy = tap / 3, dx = tap - dy * 3;
        int ib = icl * 190 + (2 * qy + dy) * 19 + 2 * qx + dx;
        float iv00 = in_s[ib], iv01 = in_s[ib + 1];
        float iv10 = in_s[ib + 19], iv11 = in_s[ib + 20];
        const float4* w4 = (const float4*)&w_s[(icl * 9 + tap) * 128 + ocg * 16];
        float wv[16];
#pragma unroll
        for (int u4 = 0; u4 < 4; u4++) {
          float4 w = w4[u4];
          wv[u4 * 4 + 0] = w.x; wv[u4 * 4 + 1] = w.y; wv[u4 * 4 + 2] = w.z; wv[u4 * 4 + 3] = w.w;
        }
#pragma unroll
        for (int u = 0; u < 16; u++) {
          acc[u][0] = fmaf(wv[u], iv00, acc[u][0]);
          acc[u][1] = fmaf(wv[u], iv01, acc[u][1]);
          acc[u][2] = fmaf(wv[u], iv10, acc[u][2]);
          acc[u][3] = fmaf(wv[u], iv11, acc[u][3]);
        }
      }
    }
    __syncthreads();
  }

  // relu(acc + b3) dot wf, partial over this thread's 16 oc
  float part[4] = {0.f, 0.f, 0.f, 0.f};
#pragma unroll
  for (int u = 0; u < 16; u++) {
    int oc = ocg * 16 + u;
    float bv = b3[oc], wfv = wf[oc];
#pragma unroll
    for (int pt = 0; pt < 4; pt++) {
      float v = fmaxf(acc[u][pt] + bv, 0.f);
      part[pt] = fmaf(v, wfv, part[pt]);
    }
  }
#pragma unroll
  for (int pt = 0; pt < 4; pt++) {
    int ly = 2 * qy + (pt >> 1), lx = 2 * qx + (pt & 1);
    ps[ocg * 128 + ly * 16 + lx] = part[pt];
  }
  __syncthreads();

  if (tid < 128) {
    float sv = bf[0];
#pragma unroll
    for (int o = 0; o < 8; o++) sv += ps[o * 128 + tid];
    int ly = tid >> 4, lx = tid & 15;
    shead[(size_t)b2 * 1024 + (ty0 + ly) * 32 + (tx0 + lx)] = sv;
  }
}

// ---------------------------------------------------------------------------
// Stage C: loss partials + clip + chamfer per b2. Mask m(y,x) = mq4[y]*mt4[x]
// (maxpool^2 of outer product of nonneg masks).
// ---------------------------------------------------------------------------
__global__ __launch_bounds__(256) void head_final_kernel(
    const float* __restrict__ shead, const float* __restrict__ qm,
    const float* __restrict__ pm, const float* __restrict__ nm,
    float* __restrict__ out, float* __restrict__ loss_ws)
{
  int b2 = blockIdx.x, b = b2 & 31, g = b2 >> 5;
  const float* qmv = qm + b * 128;
  const float* tmv = (g ? nm : pm) + b * 128;

  __shared__ float mq4[32], mt4[32];
  __shared__ float red[256];
  __shared__ float rowv[32], rowm[32];

  int tid = threadIdx.x;
  if (tid < 32) {
    float a = qmv[tid * 4];
    a = fmaxf(a, qmv[tid * 4 + 1]); a = fmaxf(a, qmv[tid * 4 + 2]); a = fmaxf(a, qmv[tid * 4 + 3]);
    mq4[tid] = a;
    float c = tmv[tid * 4];
    c = fmaxf(c, tmv[tid * 4 + 1]); c = fmaxf(c, tmv[tid * 4 + 2]); c = fmaxf(c, tmv[tid * 4 + 3]);
    mt4[tid] = c;
  }
  __syncthreads();

  const float* s = shead + (size_t)b2 * 1024;
  float lp = 0.f;
#pragma unroll
  for (int r = 0; r < 4; r++) {
    float v = s[tid + 256 * r];
    lp += fmaxf(-1.f - v, 0.f) + fmaxf(v - 1.f, 0.f);
  }
  red[tid] = lp;
  __syncthreads();
  for (int off = 128; off; off >>= 1) {
    if (tid < off) red[tid] += red[tid + off];
    __syncthreads();
  }
  if (tid == 0) loss_ws[b2] = red[0];

  if (tid < 32) {
    int y = tid;
    float mqy = mq4[y];
    float rmax = -INFINITY, mm = 0.f;
    for (int x = 0; x < 32; x++) {
      float m = mqy * mt4[x];
      mm = fmaxf(mm, m);
      float v = s[y * 32 + x];
      v = fminf(fmaxf(v, -1.f), 1.f);
      rmax = fmaxf(rmax, m > 0.f ? v : -INFINITY);
    }
    rowv[y] = (mm > 0.f) ? rmax : 0.f;
    rowm[y] = mm;
  }
  __syncthreads();
  if (tid == 0) {
    float ss = 0.f, sm = 0.f;
    for (int y = 0; y < 32; y++) { ss += rowv[y]; sm += rowm[y]; }
    out[b2] = ss / sm;
  }
}

__global__ void loss_sum_kernel(const float* __restrict__ loss_ws, float* __restrict__ out)
{
  float v = loss_ws[threadIdx.x];
#pragma unroll
  for (int off = 32; off >= 1; off >>= 1) v += __shfl_down(v, off);
  if (threadIdx.x == 0) out[64] = v;
}

// ---------------------------------------------------------------------------
extern "C" void kernel_launch(void* const* d_in, const int* in_sizes, int n_in,
                              void* d_out, int out_size, void* d_ws, size_t ws_size,
                              hipStream_t stream)
{
  (void)in_sizes; (void)n_in; (void)out_size; (void)ws_size;
  const float* A   = (const float*)d_in[0];
  const float* P   = (const float*)d_in[1];
  const float* Nn  = (const float*)d_in[2];
  const float* qm  = (const float*)d_in[3];
  const float* pm  = (const float*)d_in[4];
  const float* nm  = (const float*)d_in[5];
  const float* w1  = (const float*)d_in[6];
  const float* b1  = (const float*)d_in[7];
  const float* w2  = (const float*)d_in[8];
  const float* b2w = (const float*)d_in[9];
  const float* w3  = (const float*)d_in[10];
  const float* b3  = (const float*)d_in[11];
  const float* wf  = (const float*)d_in[12];
  const float* bf  = (const float*)d_in[13];
  float* out = (float*)d_out;

  char* ws = (char*)d_ws;
  float* sim   = (float*)(ws);                                        // 4 MB
  float* x1    = (float*)(ws + (4u << 20));                           // 32 MB
  float* x2    = (float*)(ws + (4u << 20) + (32u << 20));             // 16 MB
  float* shead = (float*)(ws + (4u << 20) + (32u << 20) + (16u << 20));   // 256 KB
  float* lws   = (float*)(ws + (4u << 20) + (32u << 20) + (16u << 20) + (1u << 20));

  sim_kernel<<<dim3(8, 8, 64), 256, 0, stream>>>(A, P, Nn, qm, pm, nm, sim);
  conv1_kernel<<<1024, 256, 0, stream>>>(sim, w1, b1, x1);
  conv2_kernel<<<dim3(16, 64), 256, 0, stream>>>(x1, w2, b2w, x2);
  conv3_kernel<<<dim3(8, 64), 256, 0, stream>>>(x2, w3, b3, wf, bf, shead);
  head_final_kernel<<<64, 256, 0, stream>>>(shead, qm, pm, nm, out, lws);
  loss_sum_kernel<<<1, 64, 0, stream>>>(lws, out);
}

// Round 2
// 516.931 us; speedup vs baseline: 3.4557x; 3.4557x over previous
//
#include <hip/hip_runtime.h>
#include <math.h>

// Problem constants: B=32, T=128, R=9, D=512. 64 pairs (32 pos + 32 neg).
#define BTRD (128*9*512)

typedef _Float16 half8 __attribute__((ext_vector_type(8)));
typedef _Float16 half4 __attribute__((ext_vector_type(4)));
typedef float f32x4 __attribute__((ext_vector_type(4)));

__device__ __forceinline__ void gload16(const _Float16* g, const _Float16* l) {
  __builtin_amdgcn_global_load_lds(
      (const __attribute__((address_space(1))) void*)g,
      (__attribute__((address_space(3))) void*)l, 16, 0, 0);
}

// ---------------------------------------------------------------------------
// fp32 -> f16 conversion prepass (memory-bound, ~18.9M elems per input)
// ---------------------------------------------------------------------------
__global__ __launch_bounds__(256) void cvt_f16_kernel(
    const float* __restrict__ in, _Float16* __restrict__ out)
{
  int idx = blockIdx.x * 256 + threadIdx.x;   // n4 = BTRD*32/4 = 4718592
  float4 v = ((const float4*)in)[idx];
  half4 h = { (_Float16)v.x, (_Float16)v.y, (_Float16)v.z, (_Float16)v.w };
  ((half4*)out)[idx] = h;
}

// ---------------------------------------------------------------------------
// Stage A (MFMA): sim[pb,i,j] = mean_o max_p dot(Q[b,i,o,:], T[b,j,p,:]).
// Block = 16i x 128j (4 waves, each 16i x 32j). p outer; acc[9o][2] per lane;
// running max over p in mx[9][2]. K chunked by 64 into LDS via global_load_lds
// (linear dest, XOR-swizzled global source; reads apply same swizzle).
// ---------------------------------------------------------------------------
__global__ __launch_bounds__(256, 2) void sim_mfma_kernel(
    const _Float16* __restrict__ Qf, const _Float16* __restrict__ Pf,
    const _Float16* __restrict__ Nf,
    const float* __restrict__ qm, const float* __restrict__ pm,
    const float* __restrict__ nm, float* __restrict__ simout)
{
  __shared__ _Float16 A_s[144 * 64];   // [r=ii*9+o][64 k] swizzled chunks
  __shared__ _Float16 B_s[128 * 64];   // [j][64 k] swizzled chunks

  int pb = blockIdx.y;
  int b = pb & 31, g = pb >> 5;
  const _Float16* Q = Qf + (size_t)b * BTRD;
  const _Float16* T = (g ? Nf : Pf) + (size_t)b * BTRD;
  int i0 = blockIdx.x * 16;

  int tid = threadIdx.x;
  int w = tid >> 6, lane = tid & 63;
  int lrow = lane & 15, lk8 = lane >> 4;

  f32x4 mx[9][2];
#pragma unroll
  for (int o = 0; o < 9; o++)
#pragma unroll
    for (int q = 0; q < 2; q++)
      mx[o][q] = (f32x4){-INFINITY, -INFINITY, -INFINITY, -INFINITY};

  for (int p = 0; p < 9; p++) {
    f32x4 acc[9][2];
#pragma unroll
    for (int o = 0; o < 9; o++)
#pragma unroll
      for (int q = 0; q < 2; q++)
        acc[o][q] = (f32x4){0.f, 0.f, 0.f, 0.f};

    for (int kc = 0; kc < 8; kc++) {
      int k0 = kc << 6;
      // stage A: 144 rows x 64 f16 = 1152 16B-chunks = 18 wave-batches
      for (int n = w; n < 18; n += 4) {
        int D = (n << 6) + lane;
        int r = D >> 3, d = D & 7;
        const _Float16* src = Q + (((size_t)(i0 * 9 + r)) << 9) + k0 + ((d ^ (r & 7)) << 3);
        gload16(src, A_s + (n << 9));
      }
      // stage B: 128 rows x 64 f16 = 1024 chunks = 16 wave-batches
      for (int n = w; n < 16; n += 4) {
        int D = (n << 6) + lane;
        int j = D >> 3, d = D & 7;
        const _Float16* src = T + (((size_t)(j * 9 + p)) << 9) + k0 + ((d ^ (j & 7)) << 3);
        gload16(src, B_s + (n << 9));
      }
      __syncthreads();

#pragma unroll
      for (int kk2 = 0; kk2 < 2; kk2++) {
        int dlog = lk8 + (kk2 << 2);
        int j0w = (w << 5) + lrow;
        int j1w = j0w + 16;
        half8 b0 = *(const half8*)&B_s[(j0w << 6) + ((dlog ^ (j0w & 7)) << 3)];
        half8 b1 = *(const half8*)&B_s[(j1w << 6) + ((dlog ^ (j1w & 7)) << 3)];
#pragma unroll
        for (int o = 0; o < 9; o++) {
          int r = lrow * 9 + o;
          half8 a = *(const half8*)&A_s[(r << 6) + ((dlog ^ (r & 7)) << 3)];
          acc[o][0] = __builtin_amdgcn_mfma_f32_16x16x32_f16(a, b0, acc[o][0], 0, 0, 0);
          acc[o][1] = __builtin_amdgcn_mfma_f32_16x16x32_f16(a, b1, acc[o][1], 0, 0, 0);
        }
      }
      __syncthreads();
    }

#pragma unroll
    for (int o = 0; o < 9; o++)
#pragma unroll
      for (int q = 0; q < 2; q++) {
#pragma unroll
        for (int e = 0; e < 4; e++)
          mx[o][q][e] = fmaxf(mx[o][q][e], acc[o][q][e]);
      }
  }

  const float* tm = (g ? nm : pm) + b * 128;
  const float* qmv = qm + b * 128;
  const float inv9 = 1.0f / 9.0f;
#pragma unroll
  for (int q = 0; q < 2; q++) {
    f32x4 sv = mx[0][q];
#pragma unroll
    for (int o = 1; o < 9; o++) sv += mx[o][q];
    sv *= inv9;
    int j = (w << 5) + (q << 4) + lrow;
    float tmv = tm[j];
#pragma unroll
    for (int e = 0; e < 4; e++) {
      int i = i0 + (lk8 << 2) + e;
      float m = qmv[i] * tmv;
      simout[((size_t)pb << 14) + (i << 7) + j] = (m > 0.f) ? sv[e] : 0.f;
    }
  }
}

// ---------------------------------------------------------------------------
// Stage B1: conv1(3x3, 1->32) + bias + relu + maxpool2.
// ---------------------------------------------------------------------------
__global__ __launch_bounds__(256) void conv1_kernel(
    const float* __restrict__ sim, const float* __restrict__ w1,
    const float* __restrict__ b1, float* __restrict__ x1)
{
  __shared__ float w_s[288];
  __shared__ float b_s[32];
  int tid = threadIdx.x;
  for (int e = tid; e < 288; e += 256) w_s[e] = w1[e];
  if (tid < 32) b_s[tid] = b1[tid];
  __syncthreads();

  int idx = blockIdx.x * 256 + tid;       // 64*64*64 total
  int x = idx & 63, y = (idx >> 6) & 63, b2 = idx >> 12;
  const float* sb = sim + (size_t)b2 * 16384;

  float patch[4][4];
#pragma unroll
  for (int r = 0; r < 4; r++) {
    int Y = 2 * y - 1 + r;
#pragma unroll
    for (int c = 0; c < 4; c++) {
      int X = 2 * x - 1 + c;
      patch[r][c] = (Y >= 0 && Y < 128 && X >= 0 && X < 128) ? sb[Y * 128 + X] : 0.f;
    }
  }

  for (int oc = 0; oc < 32; oc++) {
    float c00 = 0, c01 = 0, c10 = 0, c11 = 0;
#pragma unroll
    for (int tap = 0; tap < 9; tap++) {
      int dy = tap / 3, dx = tap - dy * 3;
      float w = w_s[oc * 9 + tap];
      c00 = fmaf(w, patch[dy][dx], c00);
      c01 = fmaf(w, patch[dy][dx + 1], c01);
      c10 = fmaf(w, patch[dy + 1][dx], c10);
      c11 = fmaf(w, patch[dy + 1][dx + 1], c11);
    }
    float v = fmaxf(fmaxf(c00, c01), fmaxf(c10, c11)) + b_s[oc];
    v = fmaxf(v, 0.f);
    x1[(((size_t)b2 * 32 + oc) * 64 + y) * 64 + x] = v;
  }
}

// ---------------------------------------------------------------------------
// Stage B2: conv2(3x3, 32->64) + bias + relu + maxpool2.
// ---------------------------------------------------------------------------
__global__ __launch_bounds__(256, 2) void conv2_kernel(
    const float* __restrict__ x1, const float* __restrict__ w2,
    const float* __restrict__ bb, float* __restrict__ x2)
{
  int b2 = blockIdx.y;
  int t = blockIdx.x;                 // 0..15
  int ty0 = (t >> 2) * 16, tx0 = (t & 3) * 16;

  __shared__ float in_s[8 * 18 * 19];
  __shared__ float w_s[8 * 9 * 64];

  int tid = threadIdx.x;
  int ocg = tid >> 6;
  int qid = tid & 63;
  int qy = qid >> 3, qx = qid & 7;

  float acc[16][4];
#pragma unroll
  for (int u = 0; u < 16; u++) { acc[u][0] = 0; acc[u][1] = 0; acc[u][2] = 0; acc[u][3] = 0; }

  for (int ic0 = 0; ic0 < 32; ic0 += 8) {
    for (int e = tid; e < 8 * 18 * 18; e += 256) {
      int icl = e / 324; int rem = e - icl * 324;
      int row = rem / 18; int col = rem - row * 18;
      int gy = ty0 - 1 + row, gx = tx0 - 1 + col;
      float v = 0.f;
      if (gy >= 0 && gy < 64 && gx >= 0 && gx < 64)
        v = x1[(((size_t)b2 * 32 + ic0 + icl) * 64 + gy) * 64 + gx];
      in_s[icl * 342 + row * 19 + col] = v;
    }
    for (int e = tid; e < 8 * 9 * 64; e += 256) {
      int oc = e & 63, r = e >> 6;
      int icl = r / 9, tap = r - icl * 9;
      w_s[e] = w2[(oc * 32 + ic0 + icl) * 9 + tap];
    }
    __syncthreads();

    for (int icl = 0; icl < 8; ++icl) {
#pragma unroll
      for (int tap = 0; tap < 9; ++tap) {
        int dy = tap / 3, dx = tap - dy * 3;
        int ib = icl * 342 + (2 * qy + dy) * 19 + 2 * qx + dx;
        float iv00 = in_s[ib], iv01 = in_s[ib + 1];
        float iv10 = in_s[ib + 19], iv11 = in_s[ib + 20];
        const float4* w4 = (const float4*)&w_s[(icl * 9 + tap) * 64 + ocg * 16];
        float wv[16];
#pragma unroll
        for (int u4 = 0; u4 < 4; u4++) {
          float4 w = w4[u4];
          wv[u4 * 4 + 0] = w.x; wv[u4 * 4 + 1] = w.y; wv[u4 * 4 + 2] = w.z; wv[u4 * 4 + 3] = w.w;
        }
#pragma unroll
        for (int u = 0; u < 16; u++) {
          acc[u][0] = fmaf(wv[u], iv00, acc[u][0]);
          acc[u][1] = fmaf(wv[u], iv01, acc[u][1]);
          acc[u][2] = fmaf(wv[u], iv10, acc[u][2]);
          acc[u][3] = fmaf(wv[u], iv11, acc[u][3]);
        }
      }
    }
    __syncthreads();
  }

  int py = (ty0 >> 1) + qy, px = (tx0 >> 1) + qx;
#pragma unroll
  for (int u = 0; u < 16; u++) {
    int oc = ocg * 16 + u;
    float v = fmaxf(fmaxf(acc[u][0], acc[u][1]), fmaxf(acc[u][2], acc[u][3])) + bb[oc];
    v = fmaxf(v, 0.f);
    x2[(((size_t)b2 * 64 + oc) * 32 + py) * 32 + px] = v;
  }
}

// ---------------------------------------------------------------------------
// Stage B3: conv3(3x3, 64->128)+relu fused with convf(1x1,128->1)+bf.
// ---------------------------------------------------------------------------
__global__ __launch_bounds__(256, 2) void conv3_kernel(
    const float* __restrict__ x2, const float* __restrict__ w3,
    const float* __restrict__ b3, const float* __restrict__ wf,
    const float* __restrict__ bf, float* __restrict__ shead)
{
  int b2 = blockIdx.y;
  int t = blockIdx.x;                 // 0..7
  int ty0 = (t >> 1) * 8, tx0 = (t & 1) * 16;

  __shared__ float in_s[8 * 10 * 19];
  __shared__ float w_s[8 * 9 * 128];
  __shared__ float ps[8 * 128];

  int tid = threadIdx.x;
  int ocg = tid >> 5;
  int qid = tid & 31;
  int qy = qid >> 3, qx = qid & 7;

  float acc[16][4];
#pragma unroll
  for (int u = 0; u < 16; u++) { acc[u][0] = 0; acc[u][1] = 0; acc[u][2] = 0; acc[u][3] = 0; }

  for (int ic0 = 0; ic0 < 64; ic0 += 8) {
    for (int e = tid; e < 8 * 10 * 18; e += 256) {
      int icl = e / 180; int rem = e - icl * 180;
      int row = rem / 18; int col = rem - row * 18;
      int gy = ty0 - 1 + row, gx = tx0 - 1 + col;
      float v = 0.f;
      if (gy >= 0 && gy < 32 && gx >= 0 && gx < 32)
        v = x2[(((size_t)b2 * 64 + ic0 + icl) * 32 + gy) * 32 + gx];
      in_s[icl * 190 + row * 19 + col] = v;
    }
    for (int e = tid; e < 8 * 9 * 128; e += 256) {
      int oc = e & 127, r = e >> 7;
      int icl = r / 9, tap = r - icl * 9;
      w_s[e] = w3[(oc * 64 + ic0 + icl) * 9 + tap];
    }
    __syncthreads();

    for (int icl = 0; icl < 8; ++icl) {
#pragma unroll
      for (int tap = 0; tap < 9; ++tap) {
        int dy = tap / 3, dx = tap - dy * 3;
        int ib = icl * 190 + (2 * qy + dy) * 19 + 2 * qx + dx;
        float iv00 = in_s[ib], iv01 = in_s[ib + 1];
        float iv10 = in_s[ib + 19], iv11 = in_s[ib + 20];
        const float4* w4 = (const float4*)&w_s[(icl * 9 + tap) * 128 + ocg * 16];
        float wv[16];
#pragma unroll
        for (int u4 = 0; u4 < 4; u4++) {
          float4 w = w4[u4];
          wv[u4 * 4 + 0] = w.x; wv[u4 * 4 + 1] = w.y; wv[u4 * 4 + 2] = w.z; wv[u4 * 4 + 3] = w.w;
        }
#pragma unroll
        for (int u = 0; u < 16; u++) {
          acc[u][0] = fmaf(wv[u], iv00, acc[u][0]);
          acc[u][1] = fmaf(wv[u], iv01, acc[u][1]);
          acc[u][2] = fmaf(wv[u], iv10, acc[u][2]);
          acc[u][3] = fmaf(wv[u], iv11, acc[u][3]);
        }
      }
    }
    __syncthreads();
  }

  float part[4] = {0.f, 0.f, 0.f, 0.f};
#pragma unroll
  for (int u = 0; u < 16; u++) {
    int oc = ocg * 16 + u;
    float bv = b3[oc], wfv = wf[oc];
#pragma unroll
    for (int pt = 0; pt < 4; pt++) {
      float v = fmaxf(acc[u][pt] + bv, 0.f);
      part[pt] = fmaf(v, wfv, part[pt]);
    }
  }
#pragma unroll
  for (int pt = 0; pt < 4; pt++) {
    int ly = 2 * qy + (pt >> 1), lx = 2 * qx + (pt & 1);
    ps[ocg * 128 + ly * 16 + lx] = part[pt];
  }
  __syncthreads();

  if (tid < 128) {
    float sv = bf[0];
#pragma unroll
    for (int o = 0; o < 8; o++) sv += ps[o * 128 + tid];
    int ly = tid >> 4, lx = tid & 15;
    shead[(size_t)b2 * 1024 + (ty0 + ly) * 32 + (tx0 + lx)] = sv;
  }
}

// ---------------------------------------------------------------------------
// Stage C: loss partials + clip + chamfer per b2.
// ---------------------------------------------------------------------------
__global__ __launch_bounds__(256) void head_final_kernel(
    const float* __restrict__ shead, const float* __restrict__ qm,
    const float* __restrict__ pm, const float* __restrict__ nm,
    float* __restrict__ out, float* __restrict__ loss_ws)
{
  int b2 = blockIdx.x, b = b2 & 31, g = b2 >> 5;
  const float* qmv = qm + b * 128;
  const float* tmv = (g ? nm : pm) + b * 128;

  __shared__ float mq4[32], mt4[32];
  __shared__ float red[256];
  __shared__ float rowv[32], rowm[32];

  int tid = threadIdx.x;
  if (tid < 32) {
    float a = qmv[tid * 4];
    a = fmaxf(a, qmv[tid * 4 + 1]); a = fmaxf(a, qmv[tid * 4 + 2]); a = fmaxf(a, qmv[tid * 4 + 3]);
    mq4[tid] = a;
    float c = tmv[tid * 4];
    c = fmaxf(c, tmv[tid * 4 + 1]); c = fmaxf(c, tmv[tid * 4 + 2]); c = fmaxf(c, tmv[tid * 4 + 3]);
    mt4[tid] = c;
  }
  __syncthreads();

  const float* s = shead + (size_t)b2 * 1024;
  float lp = 0.f;
#pragma unroll
  for (int r = 0; r < 4; r++) {
    float v = s[tid + 256 * r];
    lp += fmaxf(-1.f - v, 0.f) + fmaxf(v - 1.f, 0.f);
  }
  red[tid] = lp;
  __syncthreads();
  for (int off = 128; off; off >>= 1) {
    if (tid < off) red[tid] += red[tid + off];
    __syncthreads();
  }
  if (tid == 0) loss_ws[b2] = red[0];

  if (tid < 32) {
    int y = tid;
    float mqy = mq4[y];
    float rmax = -INFINITY, mm = 0.f;
    for (int x = 0; x < 32; x++) {
      float m = mqy * mt4[x];
      mm = fmaxf(mm, m);
      float v = s[y * 32 + x];
      v = fminf(fmaxf(v, -1.f), 1.f);
      rmax = fmaxf(rmax, m > 0.f ? v : -INFINITY);
    }
    rowv[y] = (mm > 0.f) ? rmax : 0.f;
    rowm[y] = mm;
  }
  __syncthreads();
  if (tid == 0) {
    float ss = 0.f, sm = 0.f;
    for (int y = 0; y < 32; y++) { ss += rowv[y]; sm += rowm[y]; }
    out[b2] = ss / sm;
  }
}

__global__ void loss_sum_kernel(const float* __restrict__ loss_ws, float* __restrict__ out)
{
  float v = loss_ws[threadIdx.x];
#pragma unroll
  for (int off = 32; off >= 1; off >>= 1) v += __shfl_down(v, off);
  if (threadIdx.x == 0) out[64] = v;
}

// ---------------------------------------------------------------------------
extern "C" void kernel_launch(void* const* d_in, const int* in_sizes, int n_in,
                              void* d_out, int out_size, void* d_ws, size_t ws_size,
                              hipStream_t stream)
{
  (void)in_sizes; (void)n_in; (void)out_size; (void)ws_size;
  const float* A   = (const float*)d_in[0];
  const float* P   = (const float*)d_in[1];
  const float* Nn  = (const float*)d_in[2];
  const float* qm  = (const float*)d_in[3];
  const float* pm  = (const float*)d_in[4];
  const float* nm  = (const float*)d_in[5];
  const float* w1  = (const float*)d_in[6];
  const float* b1  = (const float*)d_in[7];
  const float* w2  = (const float*)d_in[8];
  const float* b2w = (const float*)d_in[9];
  const float* w3  = (const float*)d_in[10];
  const float* b3  = (const float*)d_in[11];
  const float* wf  = (const float*)d_in[12];
  const float* bf  = (const float*)d_in[13];
  float* out = (float*)d_out;

  const size_t F16SZ = (size_t)BTRD * 32 * sizeof(_Float16);  // 37,748,736 B
  char* ws = (char*)d_ws;
  _Float16* Qf = (_Float16*)(ws);
  _Float16* Pf = (_Float16*)(ws + F16SZ);
  _Float16* Nf = (_Float16*)(ws + 2 * F16SZ);
  char* ws2 = ws + 3 * F16SZ;
  float* sim   = (float*)(ws2);
  float* x1    = (float*)(ws2 + (4u << 20));
  float* x2    = (float*)(ws2 + (4u << 20) + (32u << 20));
  float* shead = (float*)(ws2 + (4u << 20) + (32u << 20) + (16u << 20));
  float* lws   = (float*)(ws2 + (4u << 20) + (32u << 20) + (16u << 20) + (1u << 20));

  // fp32 -> f16 conversion (3 x 18.9M elems, 4/thread)
  cvt_f16_kernel<<<18432, 256, 0, stream>>>(A, Qf);
  cvt_f16_kernel<<<18432, 256, 0, stream>>>(P, Pf);
  cvt_f16_kernel<<<18432, 256, 0, stream>>>(Nn, Nf);

  sim_mfma_kernel<<<dim3(8, 64), 256, 0, stream>>>(Qf, Pf, Nf, qm, pm, nm, sim);
  conv1_kernel<<<1024, 256, 0, stream>>>(sim, w1, b1, x1);
  conv2_kernel<<<dim3(16, 64), 256, 0, stream>>>(x1, w2, b2w, x2);
  conv3_kernel<<<dim3(8, 64), 256, 0, stream>>>(x2, w3, b3, wf, bf, shead);
  head_final_kernel<<<64, 256, 0, stream>>>(shead, qm, pm, nm, out, lws);
  loss_sum_kernel<<<1, 64, 0, stream>>>(lws, out);
}

// Round 3
// 264.440 us; speedup vs baseline: 6.7552x; 1.9548x over previous
//
#include <hip/hip_runtime.h>
#include <math.h>

// Problem constants: B=32, T=128, R=9, D=512. 64 pairs (32 pos + 32 neg).
#define BTRD (128*9*512)

typedef _Float16 half8 __attribute__((ext_vector_type(8)));
typedef _Float16 half4 __attribute__((ext_vector_type(4)));
typedef float f32x4 __attribute__((ext_vector_type(4)));

__device__ __forceinline__ void gload16(const _Float16* g, const _Float16* l) {
  __builtin_amdgcn_global_load_lds(
      (const __attribute__((address_space(1))) void*)g,
      (__attribute__((address_space(3))) void*)l, 16, 0, 0);
}

// ---------------------------------------------------------------------------
// fp32 -> f16 conversion prepass
// ---------------------------------------------------------------------------
__global__ __launch_bounds__(256) void cvt_f16_kernel(
    const float* __restrict__ in, _Float16* __restrict__ out)
{
  int idx = blockIdx.x * 256 + threadIdx.x;
  float4 v = ((const float4*)in)[idx];
  half4 h = { (_Float16)v.x, (_Float16)v.y, (_Float16)v.z, (_Float16)v.w };
  ((half4*)out)[idx] = h;
}

// ---------------------------------------------------------------------------
// Weight transform: w2 (64,32,3,3) -> w2t[tap][oc][ic32] f16 (18432)
//                   w3 (128,64,3,3) -> w3t[tap][oc][ic64] f16 (73728)
// ---------------------------------------------------------------------------
__global__ __launch_bounds__(256) void wtrans_kernel(
    const float* __restrict__ w2, const float* __restrict__ w3,
    _Float16* __restrict__ w2t, _Float16* __restrict__ w3t)
{
  int idx = blockIdx.x * 256 + threadIdx.x;
  if (idx < 18432) {
    int tap = idx >> 11, oc = (idx >> 5) & 63, ic = idx & 31;
    w2t[idx] = (_Float16)w2[(oc * 32 + ic) * 9 + tap];
  } else if (idx < 18432 + 73728) {
    int j = idx - 18432;
    int tap = j >> 13, oc = (j >> 6) & 127, ic = j & 63;
    w3t[j] = (_Float16)w3[(oc * 64 + ic) * 9 + tap];
  }
}

// ---------------------------------------------------------------------------
// Stage A (MFMA): sim[pb,i,j] = mean_o max_p dot(Q[b,i,o,:], T[b,j,p,:]).
// ---------------------------------------------------------------------------
__global__ __launch_bounds__(256, 2) void sim_mfma_kernel(
    const _Float16* __restrict__ Qf, const _Float16* __restrict__ Pf,
    const _Float16* __restrict__ Nf,
    const float* __restrict__ qm, const float* __restrict__ pm,
    const float* __restrict__ nm, float* __restrict__ simout)
{
  __shared__ _Float16 A_s[144 * 64];
  __shared__ _Float16 B_s[128 * 64];

  int pb = blockIdx.y;
  int b = pb & 31, g = pb >> 5;
  const _Float16* Q = Qf + (size_t)b * BTRD;
  const _Float16* T = (g ? Nf : Pf) + (size_t)b * BTRD;
  int i0 = blockIdx.x * 16;

  int tid = threadIdx.x;
  int w = tid >> 6, lane = tid & 63;
  int lrow = lane & 15, lk8 = lane >> 4;

  f32x4 mx[9][2];
#pragma unroll
  for (int o = 0; o < 9; o++)
#pragma unroll
    for (int q = 0; q < 2; q++)
      mx[o][q] = (f32x4){-INFINITY, -INFINITY, -INFINITY, -INFINITY};

  for (int p = 0; p < 9; p++) {
    f32x4 acc[9][2];
#pragma unroll
    for (int o = 0; o < 9; o++)
#pragma unroll
      for (int q = 0; q < 2; q++)
        acc[o][q] = (f32x4){0.f, 0.f, 0.f, 0.f};

    for (int kc = 0; kc < 8; kc++) {
      int k0 = kc << 6;
      for (int n = w; n < 18; n += 4) {
        int D = (n << 6) + lane;
        int r = D >> 3, d = D & 7;
        const _Float16* src = Q + (((size_t)(i0 * 9 + r)) << 9) + k0 + ((d ^ (r & 7)) << 3);
        gload16(src, A_s + (n << 9));
      }
      for (int n = w; n < 16; n += 4) {
        int D = (n << 6) + lane;
        int j = D >> 3, d = D & 7;
        const _Float16* src = T + (((size_t)(j * 9 + p)) << 9) + k0 + ((d ^ (j & 7)) << 3);
        gload16(src, B_s + (n << 9));
      }
      __syncthreads();

#pragma unroll
      for (int kk2 = 0; kk2 < 2; kk2++) {
        int dlog = lk8 + (kk2 << 2);
        int j0w = (w << 5) + lrow;
        int j1w = j0w + 16;
        half8 b0 = *(const half8*)&B_s[(j0w << 6) + ((dlog ^ (j0w & 7)) << 3)];
        half8 b1 = *(const half8*)&B_s[(j1w << 6) + ((dlog ^ (j1w & 7)) << 3)];
#pragma unroll
        for (int o = 0; o < 9; o++) {
          int r = lrow * 9 + o;
          half8 a = *(const half8*)&A_s[(r << 6) + ((dlog ^ (r & 7)) << 3)];
          acc[o][0] = __builtin_amdgcn_mfma_f32_16x16x32_f16(a, b0, acc[o][0], 0, 0, 0);
          acc[o][1] = __builtin_amdgcn_mfma_f32_16x16x32_f16(a, b1, acc[o][1], 0, 0, 0);
        }
      }
      __syncthreads();
    }

#pragma unroll
    for (int o = 0; o < 9; o++)
#pragma unroll
      for (int q = 0; q < 2; q++) {
#pragma unroll
        for (int e = 0; e < 4; e++)
          mx[o][q][e] = fmaxf(mx[o][q][e], acc[o][q][e]);
      }
  }

  const float* tm = (g ? nm : pm) + b * 128;
  const float* qmv = qm + b * 128;
  const float inv9 = 1.0f / 9.0f;
#pragma unroll
  for (int q = 0; q < 2; q++) {
    f32x4 sv = mx[0][q];
#pragma unroll
    for (int o = 1; o < 9; o++) sv += mx[o][q];
    sv *= inv9;
    int j = (w << 5) + (q << 4) + lrow;
    float tmv = tm[j];
#pragma unroll
    for (int e = 0; e < 4; e++) {
      int i = i0 + (lk8 << 2) + e;
      float m = qmv[i] * tmv;
      simout[((size_t)pb << 14) + (i << 7) + j] = (m > 0.f) ? sv[e] : 0.f;
    }
  }
}

// ---------------------------------------------------------------------------
// Stage B1: conv1(3x3, 1->32)+bias+relu+maxpool2. Output NHWC f16.
// ---------------------------------------------------------------------------
__global__ __launch_bounds__(256) void conv1_kernel(
    const float* __restrict__ sim, const float* __restrict__ w1,
    const float* __restrict__ b1, _Float16* __restrict__ x1)
{
  __shared__ float w_s[288];
  __shared__ float b_s[32];
  int tid = threadIdx.x;
  for (int e = tid; e < 288; e += 256) w_s[e] = w1[e];
  if (tid < 32) b_s[tid] = b1[tid];
  __syncthreads();

  int idx = blockIdx.x * 256 + tid;       // 64*64*64
  int x = idx & 63, y = (idx >> 6) & 63, b2 = idx >> 12;
  const float* sb = sim + (size_t)b2 * 16384;

  float patch[4][4];
#pragma unroll
  for (int r = 0; r < 4; r++) {
    int Y = 2 * y - 1 + r;
#pragma unroll
    for (int c = 0; c < 4; c++) {
      int X = 2 * x - 1 + c;
      patch[r][c] = (Y >= 0 && Y < 128 && X >= 0 && X < 128) ? sb[Y * 128 + X] : 0.f;
    }
  }

  _Float16 vout[32];
#pragma unroll
  for (int oc = 0; oc < 32; oc++) {
    float c00 = 0, c01 = 0, c10 = 0, c11 = 0;
#pragma unroll
    for (int tap = 0; tap < 9; tap++) {
      int dy = tap / 3, dx = tap - dy * 3;
      float w = w_s[oc * 9 + tap];
      c00 = fmaf(w, patch[dy][dx], c00);
      c01 = fmaf(w, patch[dy][dx + 1], c01);
      c10 = fmaf(w, patch[dy + 1][dx], c10);
      c11 = fmaf(w, patch[dy + 1][dx + 1], c11);
    }
    float v = fmaxf(fmaxf(c00, c01), fmaxf(c10, c11)) + b_s[oc];
    vout[oc] = (_Float16)fmaxf(v, 0.f);
  }
  _Float16* dst = x1 + (((size_t)b2 * 64 + y) * 64 + x) * 32;
#pragma unroll
  for (int q = 0; q < 4; q++)
    *(half8*)(dst + q * 8) = *(half8*)&vout[q * 8];
}

// ---------------------------------------------------------------------------
// Stage B2 (MFMA): conv2(3x3,32->64)+bias+relu+maxpool2, NHWC f16 in/out.
// Block: b2 x 4 conv rows. Waves: (ypair 0..1) x (oc-half 0..1).
// Implicit GEMM: M=px (16/tile), N=oc, K=32ic per tap, 9 taps accumulated.
// in_s planar by ic-octet (conflict-free b128 reads); w_s row-padded to 40.
// ---------------------------------------------------------------------------
__global__ __launch_bounds__(256, 2) void conv2_mfma(
    const _Float16* __restrict__ x1, const _Float16* __restrict__ w2t,
    const float* __restrict__ bb, _Float16* __restrict__ x2)
{
  __shared__ _Float16 in_s[4 * 6 * 66 * 8];     // [k8][rr][px_mem][8]
  __shared__ _Float16 w_s[9 * 64 * 40];         // [tap][oc][ic(+pad)]
  __shared__ _Float16 pool_s[4][32 * 32];       // per wave [px][oc32]

  int b2 = blockIdx.y, ystrip = blockIdx.x;     // 16 strips x 4 conv rows
  int y0 = ystrip * 4;
  int tid = threadIdx.x;
  int w = tid >> 6, lane = tid & 63;
  int wyp = w >> 1, wn = w & 1;
  int lrow = lane & 15, lk8 = lane >> 4;

  {
    int px = tid >> 2, seg = tid & 3;
    const _Float16* base = x1 + ((size_t)b2 * 64) * 64 * 32;
    for (int rr = 0; rr < 6; rr++) {
      int yy = y0 - 1 + rr;
      half8 v = {};
      if (yy >= 0 && yy < 64) v = *(const half8*)(base + ((size_t)yy * 64 + px) * 32 + seg * 8);
      *(half8*)&in_s[((seg * 6 + rr) * 66 + px + 1) * 8] = v;
    }
    if (tid < 48) {
      int pr = tid >> 1, side = tid & 1;
      *(half8*)&in_s[(pr * 66 + side * 65) * 8] = (half8){};
    }
  }
  for (int e = tid; e < 2304; e += 256)
    *(half8*)&w_s[(e >> 2) * 40 + (e & 3) * 8] = *(const half8*)&w2t[e * 8];
  __syncthreads();

  f32x4 acc[2][4][2];
#pragma unroll
  for (int yr = 0; yr < 2; yr++)
#pragma unroll
    for (int xt = 0; xt < 4; xt++)
#pragma unroll
      for (int nt = 0; nt < 2; nt++)
        acc[yr][xt][nt] = (f32x4){0.f, 0.f, 0.f, 0.f};

#pragma unroll
  for (int tap = 0; tap < 9; tap++) {
    int dy = tap / 3, dx = tap - dy * 3;
    half8 bfr[2];
#pragma unroll
    for (int nt = 0; nt < 2; nt++)
      bfr[nt] = *(const half8*)&w_s[(tap * 64 + wn * 32 + nt * 16 + lrow) * 40 + lk8 * 8];
#pragma unroll
    for (int yr = 0; yr < 2; yr++) {
      int rr = 2 * wyp + yr + dy;
#pragma unroll
      for (int xt = 0; xt < 4; xt++) {
        half8 afr = *(const half8*)&in_s[((lk8 * 6 + rr) * 66 + xt * 16 + lrow + dx) * 8];
#pragma unroll
        for (int nt = 0; nt < 2; nt++)
          acc[yr][xt][nt] = __builtin_amdgcn_mfma_f32_16x16x32_f16(afr, bfr[nt], acc[yr][xt][nt], 0, 0, 0);
      }
    }
  }

  // fused bias+relu+maxpool2; C layout: row(px) = xt*16+lk8*4+e, col(oc)=lrow
  float bbv[2] = { bb[wn * 32 + lrow], bb[wn * 32 + 16 + lrow] };
#pragma unroll
  for (int nt = 0; nt < 2; nt++)
#pragma unroll
    for (int xt = 0; xt < 4; xt++)
#pragma unroll
      for (int pe = 0; pe < 2; pe++) {
        float m = fmaxf(fmaxf(acc[0][xt][nt][2 * pe], acc[0][xt][nt][2 * pe + 1]),
                        fmaxf(acc[1][xt][nt][2 * pe], acc[1][xt][nt][2 * pe + 1]));
        float v = fmaxf(m + bbv[nt], 0.f);
        int px = xt * 8 + lk8 * 2 + pe;
        pool_s[w][px * 32 + nt * 16 + lrow] = (_Float16)v;
      }
  __syncthreads();

  // coalesced NHWC store: x2[b2][py][px][oc64]
  {
    int py = ystrip * 2 + wyp;
    int px = lane & 31, half = lane >> 5;
    const _Float16* srcp = &pool_s[w][px * 32 + half * 16];
    _Float16* dst = x2 + (((size_t)b2 * 32 + py) * 32 + px) * 64 + wn * 32 + half * 16;
    *(half8*)dst = *(const half8*)srcp;
    *(half8*)(dst + 8) = *(const half8*)(srcp + 8);
  }
}

// ---------------------------------------------------------------------------
// Stage B3 (MFMA): conv3(3x3,64->128)+bias+relu fused with convf(1x1)+bf.
// Block: b2 x 4 rows; wave = 1 row x 128 oc via 4 oc-group passes.
// ---------------------------------------------------------------------------
__global__ __launch_bounds__(256, 2) void conv3_mfma(
    const _Float16* __restrict__ x2, const _Float16* __restrict__ w3t,
    const float* __restrict__ b3, const float* __restrict__ wf,
    const float* __restrict__ bf, float* __restrict__ shead)
{
  __shared__ _Float16 in_s[8 * 6 * 34 * 8];     // [k8][rr][px_mem][8]
  __shared__ _Float16 w_s[9 * 32 * 72];         // [tap][oc32][ic64(+pad)]

  int b2 = blockIdx.y, ystrip = blockIdx.x;     // 8 strips x 4 rows
  int y0 = ystrip * 4;
  int tid = threadIdx.x, w = tid >> 6, lane = tid & 63;
  int lrow = lane & 15, lk8 = lane >> 4;

  {
    int px = tid >> 3, seg = tid & 7;
    const _Float16* base = x2 + ((size_t)b2 * 32) * 32 * 64;
    for (int rr = 0; rr < 6; rr++) {
      int yy = y0 - 1 + rr;
      half8 v = {};
      if (yy >= 0 && yy < 32) v = *(const half8*)(base + ((size_t)yy * 32 + px) * 64 + seg * 8);
      *(half8*)&in_s[((seg * 6 + rr) * 34 + px + 1) * 8] = v;
    }
    if (tid < 96) {
      int pr = tid >> 1, side = tid & 1;
      *(half8*)&in_s[(pr * 34 + side * 33) * 8] = (half8){};
    }
  }

  f32x4 spart[2];
  spart[0] = (f32x4){0.f, 0.f, 0.f, 0.f};
  spart[1] = (f32x4){0.f, 0.f, 0.f, 0.f};
  int y = y0 + w;

  for (int og = 0; og < 4; og++) {
    __syncthreads();   // in_s staged (og=0) / prior og done with w_s
    for (int e = tid; e < 2304; e += 256) {
      int s = e & 7, o = (e >> 3) & 31, tap = e >> 8;
      *(half8*)&w_s[(tap * 32 + o) * 72 + s * 8] =
          *(const half8*)&w3t[((size_t)(tap * 128 + og * 32 + o)) * 64 + s * 8];
    }
    __syncthreads();

    f32x4 acc[2][2];
#pragma unroll
    for (int mt = 0; mt < 2; mt++)
#pragma unroll
      for (int nt = 0; nt < 2; nt++)
        acc[mt][nt] = (f32x4){0.f, 0.f, 0.f, 0.f};

#pragma unroll
    for (int tap = 0; tap < 9; tap++) {
      int dy = tap / 3, dx = tap - dy * 3;
#pragma unroll
      for (int kc = 0; kc < 2; kc++) {
        half8 bfr[2];
#pragma unroll
        for (int nt = 0; nt < 2; nt++)
          bfr[nt] = *(const half8*)&w_s[(tap * 32 + nt * 16 + lrow) * 72 + kc * 32 + lk8 * 8];
#pragma unroll
        for (int mt = 0; mt < 2; mt++) {
          half8 afr = *(const half8*)&in_s[(((kc * 4 + lk8) * 6 + w + dy) * 34 + mt * 16 + lrow + dx) * 8];
#pragma unroll
          for (int nt = 0; nt < 2; nt++)
            acc[mt][nt] = __builtin_amdgcn_mfma_f32_16x16x32_f16(afr, bfr[nt], acc[mt][nt], 0, 0, 0);
        }
      }
    }

#pragma unroll
    for (int nt = 0; nt < 2; nt++) {
      int oc = og * 32 + nt * 16 + lrow;
      float b3v = b3[oc], wfv = wf[oc];
#pragma unroll
      for (int mt = 0; mt < 2; mt++)
#pragma unroll
        for (int e = 0; e < 4; e++)
          spart[mt][e] = fmaf(fmaxf(acc[mt][nt][e] + b3v, 0.f), wfv, spart[mt][e]);
    }
  }

  // sum over oc cols: reduce across each 16-lane group
#pragma unroll
  for (int mt = 0; mt < 2; mt++)
#pragma unroll
    for (int e = 0; e < 4; e++) {
      float v = spart[mt][e];
      v += __shfl_xor(v, 1); v += __shfl_xor(v, 2);
      v += __shfl_xor(v, 4); v += __shfl_xor(v, 8);
      spart[mt][e] = v;
    }
  if (lrow == 0) {
    float bfv = bf[0];
#pragma unroll
    for (int mt = 0; mt < 2; mt++)
#pragma unroll
      for (int e = 0; e < 4; e++) {
        int x = mt * 16 + lk8 * 4 + e;
        shead[(size_t)b2 * 1024 + y * 32 + x] = spart[mt][e] + bfv;
      }
  }
}

// ---------------------------------------------------------------------------
// Stage C: loss partials + clip + chamfer per b2.
// ---------------------------------------------------------------------------
__global__ __launch_bounds__(256) void head_final_kernel(
    const float* __restrict__ shead, const float* __restrict__ qm,
    const float* __restrict__ pm, const float* __restrict__ nm,
    float* __restrict__ out, float* __restrict__ loss_ws)
{
  int b2 = blockIdx.x, b = b2 & 31, g = b2 >> 5;
  const float* qmv = qm + b * 128;
  const float* tmv = (g ? nm : pm) + b * 128;

  __shared__ float mq4[32], mt4[32];
  __shared__ float red[256];
  __shared__ float rowv[32], rowm[32];

  int tid = threadIdx.x;
  if (tid < 32) {
    float a = qmv[tid * 4];
    a = fmaxf(a, qmv[tid * 4 + 1]); a = fmaxf(a, qmv[tid * 4 + 2]); a = fmaxf(a, qmv[tid * 4 + 3]);
    mq4[tid] = a;
    float c = tmv[tid * 4];
    c = fmaxf(c, tmv[tid * 4 + 1]); c = fmaxf(c, tmv[tid * 4 + 2]); c = fmaxf(c, tmv[tid * 4 + 3]);
    mt4[tid] = c;
  }
  __syncthreads();

  const float* s = shead + (size_t)b2 * 1024;
  float lp = 0.f;
#pragma unroll
  for (int r = 0; r < 4; r++) {
    float v = s[tid + 256 * r];
    lp += fmaxf(-1.f - v, 0.f) + fmaxf(v - 1.f, 0.f);
  }
  red[tid] = lp;
  __syncthreads();
  for (int off = 128; off; off >>= 1) {
    if (tid < off) red[tid] += red[tid + off];
    __syncthreads();
  }
  if (tid == 0) loss_ws[b2] = red[0];

  if (tid < 32) {
    int y = tid;
    float mqy = mq4[y];
    float rmax = -INFINITY, mm = 0.f;
    for (int x = 0; x < 32; x++) {
      float m = mqy * mt4[x];
      mm = fmaxf(mm, m);
      float v = s[y * 32 + x];
      v = fminf(fmaxf(v, -1.f), 1.f);
      rmax = fmaxf(rmax, m > 0.f ? v : -INFINITY);
    }
    rowv[y] = (mm > 0.f) ? rmax : 0.f;
    rowm[y] = mm;
  }
  __syncthreads();
  if (tid == 0) {
    float ss = 0.f, sm = 0.f;
    for (int y = 0; y < 32; y++) { ss += rowv[y]; sm += rowm[y]; }
    out[b2] = ss / sm;
  }
}

__global__ void loss_sum_kernel(const float* __restrict__ loss_ws, float* __restrict__ out)
{
  float v = loss_ws[threadIdx.x];
#pragma unroll
  for (int off = 32; off >= 1; off >>= 1) v += __shfl_down(v, off);
  if (threadIdx.x == 0) out[64] = v;
}

// ---------------------------------------------------------------------------
extern "C" void kernel_launch(void* const* d_in, const int* in_sizes, int n_in,
                              void* d_out, int out_size, void* d_ws, size_t ws_size,
                              hipStream_t stream)
{
  (void)in_sizes; (void)n_in; (void)out_size; (void)ws_size;
  const float* A   = (const float*)d_in[0];
  const float* P   = (const float*)d_in[1];
  const float* Nn  = (const float*)d_in[2];
  const float* qm  = (const float*)d_in[3];
  const float* pm  = (const float*)d_in[4];
  const float* nm  = (const float*)d_in[5];
  const float* w1  = (const float*)d_in[6];
  const float* b1  = (const float*)d_in[7];
  const float* w2  = (const float*)d_in[8];
  const float* b2w = (const float*)d_in[9];
  const float* w3  = (const float*)d_in[10];
  const float* b3  = (const float*)d_in[11];
  const float* wf  = (const float*)d_in[12];
  const float* bf  = (const float*)d_in[13];
  float* out = (float*)d_out;

  const size_t F16SZ = (size_t)BTRD * 32 * sizeof(_Float16);  // 37,748,736 B
  char* ws = (char*)d_ws;
  _Float16* Qf = (_Float16*)(ws);
  _Float16* Pf = (_Float16*)(ws + F16SZ);
  _Float16* Nf = (_Float16*)(ws + 2 * F16SZ);
  char* ws2 = ws + 3 * F16SZ;
  float*     sim   = (float*)(ws2);                               // 4 MB
  _Float16*  x1    = (_Float16*)(ws2 + (4u << 20));               // 16 MB NHWC
  _Float16*  x2    = (_Float16*)(ws2 + (20u << 20));              // 8 MB NHWC
  float*     shead = (float*)(ws2 + (28u << 20));                 // 256 KB
  _Float16*  w2t   = (_Float16*)(ws2 + (29u << 20));              // 36 KB
  _Float16*  w3t   = (_Float16*)(ws2 + (29u << 20) + (256u << 10)); // 144 KB
  float*     lws   = (float*)(ws2 + (30u << 20));

  cvt_f16_kernel<<<18432, 256, 0, stream>>>(A, Qf);
  cvt_f16_kernel<<<18432, 256, 0, stream>>>(P, Pf);
  cvt_f16_kernel<<<18432, 256, 0, stream>>>(Nn, Nf);
  wtrans_kernel<<<360, 256, 0, stream>>>(w2, w3, w2t, w3t);

  sim_mfma_kernel<<<dim3(8, 64), 256, 0, stream>>>(Qf, Pf, Nf, qm, pm, nm, sim);
  conv1_kernel<<<1024, 256, 0, stream>>>(sim, w1, b1, x1);
  conv2_mfma<<<dim3(16, 64), 256, 0, stream>>>(x1, w2t, b2w, x2);
  conv3_mfma<<<dim3(8, 64), 256, 0, stream>>>(x2, w3t, b3, wf, bf, shead);
  head_final_kernel<<<64, 256, 0, stream>>>(shead, qm, pm, nm, out, lws);
  loss_sum_kernel<<<1, 64, 0, stream>>>(lws, out);
}

// Round 4
// 251.996 us; speedup vs baseline: 7.0888x; 1.0494x over previous
//
#include <hip/hip_runtime.h>
#include <math.h>

// Problem constants: B=32, T=128, R=9, D=512. 64 pairs (32 pos + 32 neg).
#define BTRD (128*9*512)

typedef _Float16 half8 __attribute__((ext_vector_type(8)));
typedef _Float16 half4 __attribute__((ext_vector_type(4)));
typedef float f32x4 __attribute__((ext_vector_type(4)));

__device__ __forceinline__ void gload16(const _Float16* g, const _Float16* l) {
  __builtin_amdgcn_global_load_lds(
      (const __attribute__((address_space(1))) void*)g,
      (__attribute__((address_space(3))) void*)l, 16, 0, 0);
}

// ---------------------------------------------------------------------------
// fp32 -> f16 conversion prepass
// ---------------------------------------------------------------------------
__global__ __launch_bounds__(256) void cvt_f16_kernel(
    const float* __restrict__ in, _Float16* __restrict__ out)
{
  int idx = blockIdx.x * 256 + threadIdx.x;
  float4 v = ((const float4*)in)[idx];
  half4 h = { (_Float16)v.x, (_Float16)v.y, (_Float16)v.z, (_Float16)v.w };
  ((half4*)out)[idx] = h;
}

// ---------------------------------------------------------------------------
// Weight transform: w2 -> w2t[tap][oc][ic32], w3 -> w3t[tap][oc][ic64] (f16)
// ---------------------------------------------------------------------------
__global__ __launch_bounds__(256) void wtrans_kernel(
    const float* __restrict__ w2, const float* __restrict__ w3,
    _Float16* __restrict__ w2t, _Float16* __restrict__ w3t)
{
  int idx = blockIdx.x * 256 + threadIdx.x;
  if (idx < 18432) {
    int tap = idx >> 11, oc = (idx >> 5) & 63, ic = idx & 31;
    w2t[idx] = (_Float16)w2[(oc * 32 + ic) * 9 + tap];
  } else if (idx < 18432 + 73728) {
    int j = idx - 18432;
    int tap = j >> 13, oc = (j >> 6) & 127, ic = j & 63;
    w3t[j] = (_Float16)w3[(oc * 64 + ic) * 9 + tap];
  }
}

// ---------------------------------------------------------------------------
// Stage A (MFMA v2): sim[pb,i,j] = mean_o max_p dot(Q[b,i,o,:], T[b,j,p,:]).
// Block = 16i x 128j, 4 waves: wave(w) = (ohalf = w>>1, jhalf = w&1),
// wave tile = 16i x 64j (J=4 MFMA tiles) over its o-subset (5 or 4 o's).
// p outer, K chunked by 32, LDS double-buffered (2-phase pipeline).
// LDS rows padded to 40 f16 (5 x 16B slots, coprime with 8 banks-slots ->
// 2-way max on ds_read_b128 = free). gload_lds dest linear; pad-slot lanes
// fetch a harmless duplicate.
// Buf layout (f16 units, per 11264-f16 buffer):
//   A: rows r=ii*9+o in [0,144): chunk c = r*5+d (c in [0,720))
//   B: rows j in [0,128):        chunk 720 + j*5+d (in [720,1360))
//   pad chunks [1360,1408) -> never read.
// ---------------------------------------------------------------------------
__device__ __forceinline__ void sim_stage(
    const _Float16* __restrict__ Q, const _Float16* __restrict__ T,
    _Float16* __restrict__ buf, int i0, int p, int k0, int tid, int lane)
{
#pragma unroll
  for (int it = 0; it < 6; it++) {
    int c = tid + it * 256;
    int wb = c - lane;              // wave-uniform chunk base
    if (wb < 1408) {
      const _Float16* src;
      if (c < 720) {
        int r = c / 5, d = c % 5;
        src = Q + ((size_t)(i0 * 9 + r) << 9) + k0 + ((d & 3) << 3);
      } else {
        int cb = c - 720;
        int j = cb / 5, d = cb % 5;
        if (cb >= 640) { j = 0; d = 0; }   // pad chunks: harmless source
        src = T + ((size_t)(j * 9 + p) << 9) + k0 + ((d & 3) << 3);
      }
      gload16(src, buf + (size_t)wb * 8);
    }
  }
}

template<int O, int OB>
__device__ __forceinline__ void sim_run(
    const _Float16* __restrict__ Q, const _Float16* __restrict__ T,
    _Float16* __restrict__ lds, int i0, int tid, int jhalf,
    int pb, int b, int g,
    const float* __restrict__ qm, const float* __restrict__ pm,
    const float* __restrict__ nm, float* __restrict__ simout)
{
  int lane = tid & 63;
  int lrow = lane & 15, lk8 = lane >> 4;

  f32x4 acc[O][4], mx[O][4];
#pragma unroll
  for (int oo = 0; oo < O; oo++)
#pragma unroll
    for (int jt = 0; jt < 4; jt++) {
      acc[oo][jt] = (f32x4){0.f, 0.f, 0.f, 0.f};
      mx[oo][jt] = (f32x4){-INFINITY, -INFINITY, -INFINITY, -INFINITY};
    }

  // prologue: stage step 0 into buf0
  sim_stage(Q, T, lds, i0, 0, 0, tid, lane);
  __syncthreads();

  for (int s = 0; s < 144; s++) {          // s = p*16 + kc
    _Float16* cur = lds + (s & 1) * 11264;
    if (s < 143) {
      int ns = s + 1;
      sim_stage(Q, T, lds + ((ns & 1) * 11264), i0, ns >> 4, (ns & 15) << 5, tid, lane);
    }

    int koff = lk8 << 3;                   // k-slot within row
    half8 bfr[4];
#pragma unroll
    for (int jt = 0; jt < 4; jt++) {
      int j = jhalf * 64 + jt * 16 + lrow;
      bfr[jt] = *(const half8*)&cur[5760 + j * 40 + koff];
    }
#pragma unroll
    for (int oo = 0; oo < O; oo++) {
      int r = lrow * 9 + OB + oo;
      half8 afr = *(const half8*)&cur[r * 40 + koff];
#pragma unroll
      for (int jt = 0; jt < 4; jt++)
        acc[oo][jt] = __builtin_amdgcn_mfma_f32_16x16x32_f16(afr, bfr[jt], acc[oo][jt], 0, 0, 0);
    }

    if ((s & 15) == 15) {                  // end of a p: fold max, reset acc
#pragma unroll
      for (int oo = 0; oo < O; oo++)
#pragma unroll
        for (int jt = 0; jt < 4; jt++) {
#pragma unroll
          for (int e = 0; e < 4; e++)
            mx[oo][jt][e] = fmaxf(mx[oo][jt][e], acc[oo][jt][e]);
          acc[oo][jt] = (f32x4){0.f, 0.f, 0.f, 0.f};
        }
    }
    __syncthreads();
  }

  // partial sum over this wave's o-subset
  f32x4 ps[4];
#pragma unroll
  for (int jt = 0; jt < 4; jt++) {
    ps[jt] = mx[0][jt];
#pragma unroll
    for (int oo = 1; oo < O; oo++) ps[jt] += mx[oo][jt];
  }

  // cross-wave o-merge through LDS (reuse buffer space)
  float* ex = (float*)lds;
  if (OB != 0) {
#pragma unroll
    for (int jt = 0; jt < 4; jt++)
      *(f32x4*)&ex[(((jhalf << 6) + lane) * 4 + jt) * 4] = ps[jt];
  }
  __syncthreads();
  if (OB == 0) {
    const float* tm = (g ? nm : pm) + b * 128;
    const float* qmv = qm + b * 128;
    const float inv9 = 1.0f / 9.0f;
#pragma unroll
    for (int jt = 0; jt < 4; jt++) {
      ps[jt] += *(const f32x4*)&ex[(((jhalf << 6) + lane) * 4 + jt) * 4];
      int j = jhalf * 64 + jt * 16 + lrow;
      float tmv = tm[j];
#pragma unroll
      for (int e = 0; e < 4; e++) {
        int i = i0 + (lk8 << 2) + e;
        float m = qmv[i] * tmv;
        simout[((size_t)pb << 14) + (i << 7) + j] = (m > 0.f) ? ps[jt][e] * inv9 : 0.f;
      }
    }
  }
}

__global__ __launch_bounds__(256, 2) void sim_mfma_kernel(
    const _Float16* __restrict__ Qf, const _Float16* __restrict__ Pf,
    const _Float16* __restrict__ Nf,
    const float* __restrict__ qm, const float* __restrict__ pm,
    const float* __restrict__ nm, float* __restrict__ simout)
{
  __shared__ _Float16 lds[2 * 11264];   // 45056 B

  // XCD-chunked remap: all 8 i-blocks of a pair live on one XCD's L2.
  int n = blockIdx.x;                   // 512 blocks = 8 xcd * 8 pb * 8 ib
  int xcd = n & 7, slot = n >> 3;
  int pb = xcd * 8 + (slot >> 3);
  int ib = slot & 7;
  int b = pb & 31, g = pb >> 5;
  const _Float16* Q = Qf + (size_t)b * BTRD;
  const _Float16* T = (g ? Nf : Pf) + (size_t)b * BTRD;
  int i0 = ib * 16;

  int tid = threadIdx.x;
  int w = tid >> 6;
  int jhalf = w & 1;
  if ((w >> 1) == 0)
    sim_run<5, 0>(Q, T, lds, i0, tid, jhalf, pb, b, g, qm, pm, nm, simout);
  else
    sim_run<4, 5>(Q, T, lds, i0, tid, jhalf, pb, b, g, qm, pm, nm, simout);
}

// ---------------------------------------------------------------------------
// Stage B1: conv1(3x3, 1->32)+bias+relu+maxpool2. Output NHWC f16.
// ---------------------------------------------------------------------------
__global__ __launch_bounds__(256) void conv1_kernel(
    const float* __restrict__ sim, const float* __restrict__ w1,
    const float* __restrict__ b1, _Float16* __restrict__ x1)
{
  __shared__ float w_s[288];
  __shared__ float b_s[32];
  int tid = threadIdx.x;
  for (int e = tid; e < 288; e += 256) w_s[e] = w1[e];
  if (tid < 32) b_s[tid] = b1[tid];
  __syncthreads();

  int idx = blockIdx.x * 256 + tid;       // 64*64*64
  int x = idx & 63, y = (idx >> 6) & 63, b2 = idx >> 12;
  const float* sb = sim + (size_t)b2 * 16384;

  float patch[4][4];
#pragma unroll
  for (int r = 0; r < 4; r++) {
    int Y = 2 * y - 1 + r;
#pragma unroll
    for (int c = 0; c < 4; c++) {
      int X = 2 * x - 1 + c;
      patch[r][c] = (Y >= 0 && Y < 128 && X >= 0 && X < 128) ? sb[Y * 128 + X] : 0.f;
    }
  }

  _Float16 vout[32];
#pragma unroll
  for (int oc = 0; oc < 32; oc++) {
    float c00 = 0, c01 = 0, c10 = 0, c11 = 0;
#pragma unroll
    for (int tap = 0; tap < 9; tap++) {
      int dy = tap / 3, dx = tap - dy * 3;
      float w = w_s[oc * 9 + tap];
      c00 = fmaf(w, patch[dy][dx], c00);
      c01 = fmaf(w, patch[dy][dx + 1], c01);
      c10 = fmaf(w, patch[dy + 1][dx], c10);
      c11 = fmaf(w, patch[dy + 1][dx + 1], c11);
    }
    float v = fmaxf(fmaxf(c00, c01), fmaxf(c10, c11)) + b_s[oc];
    vout[oc] = (_Float16)fmaxf(v, 0.f);
  }
  _Float16* dst = x1 + (((size_t)b2 * 64 + y) * 64 + x) * 32;
#pragma unroll
  for (int q = 0; q < 4; q++)
    *(half8*)(dst + q * 8) = *(half8*)&vout[q * 8];
}

// ---------------------------------------------------------------------------
// Stage B2 (MFMA): conv2(3x3,32->64)+bias+relu+maxpool2, NHWC f16 in/out.
// ---------------------------------------------------------------------------
__global__ __launch_bounds__(256, 2) void conv2_mfma(
    const _Float16* __restrict__ x1, const _Float16* __restrict__ w2t,
    const float* __restrict__ bb, _Float16* __restrict__ x2)
{
  __shared__ _Float16 in_s[4 * 6 * 66 * 8];     // [k8][rr][px_mem][8]
  __shared__ _Float16 w_s[9 * 64 * 40];         // [tap][oc][ic(+pad)]
  __shared__ _Float16 pool_s[4][32 * 32];       // per wave [px][oc32]

  int b2 = blockIdx.y, ystrip = blockIdx.x;     // 16 strips x 4 conv rows
  int y0 = ystrip * 4;
  int tid = threadIdx.x;
  int w = tid >> 6, lane = tid & 63;
  int wyp = w >> 1, wn = w & 1;
  int lrow = lane & 15, lk8 = lane >> 4;

  {
    int px = tid >> 2, seg = tid & 3;
    const _Float16* base = x1 + ((size_t)b2 * 64) * 64 * 32;
    for (int rr = 0; rr < 6; rr++) {
      int yy = y0 - 1 + rr;
      half8 v = {};
      if (yy >= 0 && yy < 64) v = *(const half8*)(base + ((size_t)yy * 64 + px) * 32 + seg * 8);
      *(half8*)&in_s[((seg * 6 + rr) * 66 + px + 1) * 8] = v;
    }
    if (tid < 48) {
      int pr = tid >> 1, side = tid & 1;
      *(half8*)&in_s[(pr * 66 + side * 65) * 8] = (half8){};
    }
  }
  for (int e = tid; e < 2304; e += 256)
    *(half8*)&w_s[(e >> 2) * 40 + (e & 3) * 8] = *(const half8*)&w2t[e * 8];
  __syncthreads();

  f32x4 acc[2][4][2];
#pragma unroll
  for (int yr = 0; yr < 2; yr++)
#pragma unroll
    for (int xt = 0; xt < 4; xt++)
#pragma unroll
      for (int nt = 0; nt < 2; nt++)
        acc[yr][xt][nt] = (f32x4){0.f, 0.f, 0.f, 0.f};

#pragma unroll
  for (int tap = 0; tap < 9; tap++) {
    int dy = tap / 3, dx = tap - dy * 3;
    half8 bfr[2];
#pragma unroll
    for (int nt = 0; nt < 2; nt++)
      bfr[nt] = *(const half8*)&w_s[(tap * 64 + wn * 32 + nt * 16 + lrow) * 40 + lk8 * 8];
#pragma unroll
    for (int yr = 0; yr < 2; yr++) {
      int rr = 2 * wyp + yr + dy;
#pragma unroll
      for (int xt = 0; xt < 4; xt++) {
        half8 afr = *(const half8*)&in_s[((lk8 * 6 + rr) * 66 + xt * 16 + lrow + dx) * 8];
#pragma unroll
        for (int nt = 0; nt < 2; nt++)
          acc[yr][xt][nt] = __builtin_amdgcn_mfma_f32_16x16x32_f16(afr, bfr[nt], acc[yr][xt][nt], 0, 0, 0);
      }
    }
  }

  float bbv[2] = { bb[wn * 32 + lrow], bb[wn * 32 + 16 + lrow] };
#pragma unroll
  for (int nt = 0; nt < 2; nt++)
#pragma unroll
    for (int xt = 0; xt < 4; xt++)
#pragma unroll
      for (int pe = 0; pe < 2; pe++) {
        float m = fmaxf(fmaxf(acc[0][xt][nt][2 * pe], acc[0][xt][nt][2 * pe + 1]),
                        fmaxf(acc[1][xt][nt][2 * pe], acc[1][xt][nt][2 * pe + 1]));
        float v = fmaxf(m + bbv[nt], 0.f);
        int px = xt * 8 + lk8 * 2 + pe;
        pool_s[w][px * 32 + nt * 16 + lrow] = (_Float16)v;
      }
  __syncthreads();

  {
    int py = ystrip * 2 + wyp;
    int px = lane & 31, half = lane >> 5;
    const _Float16* srcp = &pool_s[w][px * 32 + half * 16];
    _Float16* dst = x2 + (((size_t)b2 * 32 + py) * 32 + px) * 64 + wn * 32 + half * 16;
    *(half8*)dst = *(const half8*)srcp;
    *(half8*)(dst + 8) = *(const half8*)(srcp + 8);
  }
}

// ---------------------------------------------------------------------------
// Stage B3 (MFMA): conv3(3x3,64->128)+bias+relu fused with convf(1x1)+bf.
// ---------------------------------------------------------------------------
__global__ __launch_bounds__(256, 2) void conv3_mfma(
    const _Float16* __restrict__ x2, const _Float16* __restrict__ w3t,
    const float* __restrict__ b3, const float* __restrict__ wf,
    const float* __restrict__ bf, float* __restrict__ shead)
{
  __shared__ _Float16 in_s[8 * 6 * 34 * 8];
  __shared__ _Float16 w_s[9 * 32 * 72];

  int b2 = blockIdx.y, ystrip = blockIdx.x;
  int y0 = ystrip * 4;
  int tid = threadIdx.x, w = tid >> 6, lane = tid & 63;
  int lrow = lane & 15, lk8 = lane >> 4;

  {
    int px = tid >> 3, seg = tid & 7;
    const _Float16* base = x2 + ((size_t)b2 * 32) * 32 * 64;
    for (int rr = 0; rr < 6; rr++) {
      int yy = y0 - 1 + rr;
      half8 v = {};
      if (yy >= 0 && yy < 32) v = *(const half8*)(base + ((size_t)yy * 32 + px) * 64 + seg * 8);
      *(half8*)&in_s[((seg * 6 + rr) * 34 + px + 1) * 8] = v;
    }
    if (tid < 96) {
      int pr = tid >> 1, side = tid & 1;
      *(half8*)&in_s[(pr * 34 + side * 33) * 8] = (half8){};
    }
  }

  f32x4 spart[2];
  spart[0] = (f32x4){0.f, 0.f, 0.f, 0.f};
  spart[1] = (f32x4){0.f, 0.f, 0.f, 0.f};
  int y = y0 + w;

  for (int og = 0; og < 4; og++) {
    __syncthreads();
    for (int e = tid; e < 2304; e += 256) {
      int s = e & 7, o = (e >> 3) & 31, tap = e >> 8;
      *(half8*)&w_s[(tap * 32 + o) * 72 + s * 8] =
          *(const half8*)&w3t[((size_t)(tap * 128 + og * 32 + o)) * 64 + s * 8];
    }
    __syncthreads();

    f32x4 acc[2][2];
#pragma unroll
    for (int mt = 0; mt < 2; mt++)
#pragma unroll
      for (int nt = 0; nt < 2; nt++)
        acc[mt][nt] = (f32x4){0.f, 0.f, 0.f, 0.f};

#pragma unroll
    for (int tap = 0; tap < 9; tap++) {
      int dy = tap / 3, dx = tap - dy * 3;
#pragma unroll
      for (int kc = 0; kc < 2; kc++) {
        half8 bfr[2];
#pragma unroll
        for (int nt = 0; nt < 2; nt++)
          bfr[nt] = *(const half8*)&w_s[(tap * 32 + nt * 16 + lrow) * 72 + kc * 32 + lk8 * 8];
#pragma unroll
        for (int mt = 0; mt < 2; mt++) {
          half8 afr = *(const half8*)&in_s[(((kc * 4 + lk8) * 6 + w + dy) * 34 + mt * 16 + lrow + dx) * 8];
#pragma unroll
          for (int nt = 0; nt < 2; nt++)
            acc[mt][nt] = __builtin_amdgcn_mfma_f32_16x16x32_f16(afr, bfr[nt], acc[mt][nt], 0, 0, 0);
        }
      }
    }

#pragma unroll
    for (int nt = 0; nt < 2; nt++) {
      int oc = og * 32 + nt * 16 + lrow;
      float b3v = b3[oc], wfv = wf[oc];
#pragma unroll
      for (int mt = 0; mt < 2; mt++)
#pragma unroll
        for (int e = 0; e < 4; e++)
          spart[mt][e] = fmaf(fmaxf(acc[mt][nt][e] + b3v, 0.f), wfv, spart[mt][e]);
    }
  }

#pragma unroll
  for (int mt = 0; mt < 2; mt++)
#pragma unroll
    for (int e = 0; e < 4; e++) {
      float v = spart[mt][e];
      v += __shfl_xor(v, 1); v += __shfl_xor(v, 2);
      v += __shfl_xor(v, 4); v += __shfl_xor(v, 8);
      spart[mt][e] = v;
    }
  if (lrow == 0) {
    float bfv = bf[0];
#pragma unroll
    for (int mt = 0; mt < 2; mt++)
#pragma unroll
      for (int e = 0; e < 4; e++) {
        int x = mt * 16 + lk8 * 4 + e;
        shead[(size_t)b2 * 1024 + y * 32 + x] = spart[mt][e] + bfv;
      }
  }
}

// ---------------------------------------------------------------------------
// Stage C: loss partials + clip + chamfer per b2.
// ---------------------------------------------------------------------------
__global__ __launch_bounds__(256) void head_final_kernel(
    const float* __restrict__ shead, const float* __restrict__ qm,
    const float* __restrict__ pm, const float* __restrict__ nm,
    float* __restrict__ out, float* __restrict__ loss_ws)
{
  int b2 = blockIdx.x, b = b2 & 31, g = b2 >> 5;
  const float* qmv = qm + b * 128;
  const float* tmv = (g ? nm : pm) + b * 128;

  __shared__ float mq4[32], mt4[32];
  __shared__ float red[256];
  __shared__ float rowv[32], rowm[32];

  int tid = threadIdx.x;
  if (tid < 32) {
    float a = qmv[tid * 4];
    a = fmaxf(a, qmv[tid * 4 + 1]); a = fmaxf(a, qmv[tid * 4 + 2]); a = fmaxf(a, qmv[tid * 4 + 3]);
    mq4[tid] = a;
    float c = tmv[tid * 4];
    c = fmaxf(c, tmv[tid * 4 + 1]); c = fmaxf(c, tmv[tid * 4 + 2]); c = fmaxf(c, tmv[tid * 4 + 3]);
    mt4[tid] = c;
  }
  __syncthreads();

  const float* s = shead + (size_t)b2 * 1024;
  float lp = 0.f;
#pragma unroll
  for (int r = 0; r < 4; r++) {
    float v = s[tid + 256 * r];
    lp += fmaxf(-1.f - v, 0.f) + fmaxf(v - 1.f, 0.f);
  }
  red[tid] = lp;
  __syncthreads();
  for (int off = 128; off; off >>= 1) {
    if (tid < off) red[tid] += red[tid + off];
    __syncthreads();
  }
  if (tid == 0) loss_ws[b2] = red[0];

  if (tid < 32) {
    int y = tid;
    float mqy = mq4[y];
    float rmax = -INFINITY, mm = 0.f;
    for (int x = 0; x < 32; x++) {
      float m = mqy * mt4[x];
      mm = fmaxf(mm, m);
      float v = s[y * 32 + x];
      v = fminf(fmaxf(v, -1.f), 1.f);
      rmax = fmaxf(rmax, m > 0.f ? v : -INFINITY);
    }
    rowv[y] = (mm > 0.f) ? rmax : 0.f;
    rowm[y] = mm;
  }
  __syncthreads();
  if (tid == 0) {
    float ss = 0.f, sm = 0.f;
    for (int y = 0; y < 32; y++) { ss += rowv[y]; sm += rowm[y]; }
    out[b2] = ss / sm;
  }
}

__global__ void loss_sum_kernel(const float* __restrict__ loss_ws, float* __restrict__ out)
{
  float v = loss_ws[threadIdx.x];
#pragma unroll
  for (int off = 32; off >= 1; off >>= 1) v += __shfl_down(v, off);
  if (threadIdx.x == 0) out[64] = v;
}

// ---------------------------------------------------------------------------
extern "C" void kernel_launch(void* const* d_in, const int* in_sizes, int n_in,
                              void* d_out, int out_size, void* d_ws, size_t ws_size,
                              hipStream_t stream)
{
  (void)in_sizes; (void)n_in; (void)out_size; (void)ws_size;
  const float* A   = (const float*)d_in[0];
  const float* P   = (const float*)d_in[1];
  const float* Nn  = (const float*)d_in[2];
  const float* qm  = (const float*)d_in[3];
  const float* pm  = (const float*)d_in[4];
  const float* nm  = (const float*)d_in[5];
  const float* w1  = (const float*)d_in[6];
  const float* b1  = (const float*)d_in[7];
  const float* w2  = (const float*)d_in[8];
  const float* b2w = (const float*)d_in[9];
  const float* w3  = (const float*)d_in[10];
  const float* b3  = (const float*)d_in[11];
  const float* wf  = (const float*)d_in[12];
  const float* bf  = (const float*)d_in[13];
  float* out = (float*)d_out;

  const size_t F16SZ = (size_t)BTRD * 32 * sizeof(_Float16);  // 37,748,736 B
  char* ws = (char*)d_ws;
  _Float16* Qf = (_Float16*)(ws);
  _Float16* Pf = (_Float16*)(ws + F16SZ);
  _Float16* Nf = (_Float16*)(ws + 2 * F16SZ);
  char* ws2 = ws + 3 * F16SZ;
  float*     sim   = (float*)(ws2);                               // 4 MB
  _Float16*  x1    = (_Float16*)(ws2 + (4u << 20));               // 16 MB NHWC
  _Float16*  x2    = (_Float16*)(ws2 + (20u << 20));              // 8 MB NHWC
  float*     shead = (float*)(ws2 + (28u << 20));                 // 256 KB
  _Float16*  w2t   = (_Float16*)(ws2 + (29u << 20));              // 36 KB
  _Float16*  w3t   = (_Float16*)(ws2 + (29u << 20) + (256u << 10)); // 144 KB
  float*     lws   = (float*)(ws2 + (30u << 20));

  cvt_f16_kernel<<<18432, 256, 0, stream>>>(A, Qf);
  cvt_f16_kernel<<<18432, 256, 0, stream>>>(P, Pf);
  cvt_f16_kernel<<<18432, 256, 0, stream>>>(Nn, Nf);
  wtrans_kernel<<<360, 256, 0, stream>>>(w2, w3, w2t, w3t);

  sim_mfma_kernel<<<512, 256, 0, stream>>>(Qf, Pf, Nf, qm, pm, nm, sim);
  conv1_kernel<<<1024, 256, 0, stream>>>(sim, w1, b1, x1);
  conv2_mfma<<<dim3(16, 64), 256, 0, stream>>>(x1, w2t, b2w, x2);
  conv3_mfma<<<dim3(8, 64), 256, 0, stream>>>(x2, w3t, b3, wf, bf, shead);
  head_final_kernel<<<64, 256, 0, stream>>>(shead, qm, pm, nm, out, lws);
  loss_sum_kernel<<<1, 64, 0, stream>>>(lws, out);
}

// Round 5
// 246.177 us; speedup vs baseline: 7.2564x; 1.0236x over previous
//
#include <hip/hip_runtime.h>
#include <math.h>

// Problem constants: B=32, T=128, R=9, D=512. 64 pairs (32 pos + 32 neg).
#define BTRD (128*9*512)

typedef _Float16 half8 __attribute__((ext_vector_type(8)));
typedef _Float16 half4 __attribute__((ext_vector_type(4)));
typedef float f32x4 __attribute__((ext_vector_type(4)));

__device__ __forceinline__ void gload16(const _Float16* g, const _Float16* l) {
  __builtin_amdgcn_global_load_lds(
      (const __attribute__((address_space(1))) void*)g,
      (__attribute__((address_space(3))) void*)l, 16, 0, 0);
}

// ---------------------------------------------------------------------------
// prep: fp32->f16 cvt for A/P/N (8 floats/thread) + weight transforms, fused
// into one launch. cvt blocks: 3 x 9216; wtrans blocks: 360.
// ---------------------------------------------------------------------------
__global__ __launch_bounds__(256) void prep_kernel(
    const float* __restrict__ A, const float* __restrict__ P, const float* __restrict__ Nn,
    _Float16* __restrict__ Qf, _Float16* __restrict__ Pf, _Float16* __restrict__ Nf,
    const float* __restrict__ w2, const float* __restrict__ w3,
    _Float16* __restrict__ w2t, _Float16* __restrict__ w3t)
{
  int bid = blockIdx.x;
  if (bid < 27648) {
    int which = bid / 9216;
    const float* in = which == 0 ? A : (which == 1 ? P : Nn);
    _Float16* out = which == 0 ? Qf : (which == 1 ? Pf : Nf);
    int idx = (bid - which * 9216) * 256 + threadIdx.x;
    const float4* in4 = (const float4*)in;
    float4 a = in4[idx * 2], c = in4[idx * 2 + 1];
    half8 h = { (_Float16)a.x, (_Float16)a.y, (_Float16)a.z, (_Float16)a.w,
                (_Float16)c.x, (_Float16)c.y, (_Float16)c.z, (_Float16)c.w };
    ((half8*)out)[idx] = h;
  } else {
    int idx = (bid - 27648) * 256 + threadIdx.x;
    if (idx < 18432) {
      int tap = idx >> 11, oc = (idx >> 5) & 63, ic = idx & 31;
      w2t[idx] = (_Float16)w2[(oc * 32 + ic) * 9 + tap];
    } else if (idx < 18432 + 73728) {
      int j = idx - 18432;
      int tap = j >> 13, oc = (j >> 6) & 127, ic = j & 63;
      w3t[j] = (_Float16)w3[(oc * 64 + ic) * 9 + tap];
    }
  }
}

// ---------------------------------------------------------------------------
// Stage A (MFMA v3): sim[pb,i,j] = mean_o max_p dot(Q[b,i,o,:], T[b,j,p,:]).
// Q-tile (16i x 9o x 512k f16 = 147456B) PERSISTENT in LDS, staged once.
// T double-buffered (2 x 128j x 32k = 16384B). Total LDS = 163840B (160KiB),
// 1 block/CU. Block = 4 waves: wave = (og = w>>1 -> o-subset {0..4}/{5..8})
// x (jhalf = w&1 -> 64 j). p outer, 144 steps (9p x 16kc), 2-phase T pipeline.
// Swizzles (both-sides XOR, linear gload dest + pre-swizzled source):
//   Q: row r (1024B), 64 slots of 16B, phys_slot = log_slot ^ (r&7)
//   T: row j (64B), 4 slots, phys_slot = log_slot ^ ((j>>1)&3)
// Both read patterns: 16-lane phase -> 8 distinct 16B positions x 2 lanes
// (the R3-verified conflict-free class).
// ---------------------------------------------------------------------------
template<int O, int OB>
__device__ __forceinline__ void sim_run(
    const _Float16* __restrict__ Q, const _Float16* __restrict__ T,
    _Float16* __restrict__ lds, int i0, int tid, int jhalf,
    int pb, int b, int g,
    const float* __restrict__ qm, const float* __restrict__ pm,
    const float* __restrict__ nm, float* __restrict__ simout)
{
  int lane = tid & 63;
  int lrow = lane & 15, lk8 = lane >> 4;
  _Float16* tb0 = lds + 73728;
  _Float16* tb1 = lds + 73728 + 4096;

  // prologue: persistent Q stage (9216 chunks) + T step 0 (512 chunks)
#pragma unroll
  for (int it = 0; it < 36; it++) {
    int c = it * 256 + tid;
    int r = c >> 6, sp = c & 63;
    const _Float16* src = Q + ((size_t)(i0 * 9 + r) << 9) + ((sp ^ (r & 7)) << 3);
    gload16(src, lds + c * 8);
  }
#pragma unroll
  for (int it = 0; it < 2; it++) {
    int c = it * 256 + tid;
    int j = c >> 2, sp = c & 3;
    const _Float16* src = T + ((size_t)(j * 9) << 9) + ((sp ^ ((j >> 1) & 3)) << 3);
    gload16(src, tb0 + c * 8);
  }
  __syncthreads();

  f32x4 acc[O][4], mx[O][4];
#pragma unroll
  for (int oo = 0; oo < O; oo++)
#pragma unroll
    for (int jt = 0; jt < 4; jt++) {
      acc[oo][jt] = (f32x4){0.f, 0.f, 0.f, 0.f};
      mx[oo][jt] = (f32x4){-INFINITY, -INFINITY, -INFINITY, -INFINITY};
    }

  for (int s = 0; s < 144; s++) {          // s = p*16 + kc
    const _Float16* cur = (s & 1) ? tb1 : tb0;
    if (s < 143) {
      int ns = s + 1, np = ns >> 4, nk0 = (ns & 15) << 5;
      _Float16* nb = (ns & 1) ? tb1 : tb0;
#pragma unroll
      for (int it = 0; it < 2; it++) {
        int c = it * 256 + tid;
        int j = c >> 2, sp = c & 3;
        const _Float16* src = T + ((size_t)(j * 9 + np) << 9) + nk0 + ((sp ^ ((j >> 1) & 3)) << 3);
        gload16(src, nb + c * 8);
      }
    }

    int kc = s & 15;
    half8 bfr[4];
#pragma unroll
    for (int jt = 0; jt < 4; jt++) {
      int j = jhalf * 64 + jt * 16 + lrow;
      bfr[jt] = *(const half8*)&cur[j * 32 + ((lk8 ^ ((j >> 1) & 3)) << 3)];
    }
#pragma unroll
    for (int oo = 0; oo < O; oo++) {
      int r = lrow * 9 + OB + oo;
      half8 afr = *(const half8*)&lds[r * 512 + ((((kc << 2) + lk8) ^ (r & 7)) << 3)];
#pragma unroll
      for (int jt = 0; jt < 4; jt++)
        acc[oo][jt] = __builtin_amdgcn_mfma_f32_16x16x32_f16(afr, bfr[jt], acc[oo][jt], 0, 0, 0);
    }

    if ((s & 15) == 15) {                  // end of a p: fold max, reset acc
#pragma unroll
      for (int oo = 0; oo < O; oo++)
#pragma unroll
        for (int jt = 0; jt < 4; jt++) {
#pragma unroll
          for (int e = 0; e < 4; e++)
            mx[oo][jt][e] = fmaxf(mx[oo][jt][e], acc[oo][jt][e]);
          acc[oo][jt] = (f32x4){0.f, 0.f, 0.f, 0.f};
        }
    }
    __syncthreads();
  }

  // partial sum over this wave's o-subset
  f32x4 ps[4];
#pragma unroll
  for (int jt = 0; jt < 4; jt++) {
    ps[jt] = mx[0][jt];
#pragma unroll
    for (int oo = 1; oo < O; oo++) ps[jt] += mx[oo][jt];
  }

  // cross-wave o-merge via LDS (reuses T-buffer region, lane-contiguous)
  float* ex = (float*)(lds + 73728);
  if (OB != 0) {
#pragma unroll
    for (int jt = 0; jt < 4; jt++)
      *(f32x4*)&ex[((jt * 2 + jhalf) * 64 + lane) * 4] = ps[jt];
  }
  __syncthreads();
  if (OB == 0) {
    const float* tm = (g ? nm : pm) + b * 128;
    const float* qmv = qm + b * 128;
    const float inv9 = 1.0f / 9.0f;
#pragma unroll
    for (int jt = 0; jt < 4; jt++) {
      ps[jt] += *(const f32x4*)&ex[((jt * 2 + jhalf) * 64 + lane) * 4];
      int j = jhalf * 64 + jt * 16 + lrow;
      float tmv = tm[j];
#pragma unroll
      for (int e = 0; e < 4; e++) {
        int i = i0 + (lk8 << 2) + e;
        float m = qmv[i] * tmv;
        simout[((size_t)pb << 14) + (i << 7) + j] = (m > 0.f) ? ps[jt][e] * inv9 : 0.f;
      }
    }
  }
}

__global__ __launch_bounds__(256, 1) void sim_mfma_kernel(
    const _Float16* __restrict__ Qf, const _Float16* __restrict__ Pf,
    const _Float16* __restrict__ Nf,
    const float* __restrict__ qm, const float* __restrict__ pm,
    const float* __restrict__ nm, float* __restrict__ simout)
{
  __shared__ _Float16 lds[81920];       // 163840 B = full 160 KiB

  // XCD-chunked remap: the 8 i-blocks of a pair co-resident on one XCD.
  int n = blockIdx.x;                   // 512 = 8 xcd * 8 pb * 8 ib
  int xcd = n & 7, slot = n >> 3;
  int pb = xcd * 8 + (slot >> 3);
  int ib = slot & 7;
  int b = pb & 31, g = pb >> 5;
  const _Float16* Q = Qf + (size_t)b * BTRD;
  const _Float16* T = (g ? Nf : Pf) + (size_t)b * BTRD;
  int i0 = ib * 16;

  int tid = threadIdx.x;
  int w = tid >> 6;
  int jhalf = w & 1;
  if ((w >> 1) == 0)
    sim_run<5, 0>(Q, T, lds, i0, tid, jhalf, pb, b, g, qm, pm, nm, simout);
  else
    sim_run<4, 5>(Q, T, lds, i0, tid, jhalf, pb, b, g, qm, pm, nm, simout);
}

// ---------------------------------------------------------------------------
// Stage B1: conv1(3x3, 1->32)+bias+relu+maxpool2. Output NHWC f16.
// ---------------------------------------------------------------------------
__global__ __launch_bounds__(256) void conv1_kernel(
    const float* __restrict__ sim, const float* __restrict__ w1,
    const float* __restrict__ b1, _Float16* __restrict__ x1)
{
  __shared__ float w_s[288];
  __shared__ float b_s[32];
  int tid = threadIdx.x;
  for (int e = tid; e < 288; e += 256) w_s[e] = w1[e];
  if (tid < 32) b_s[tid] = b1[tid];
  __syncthreads();

  int idx = blockIdx.x * 256 + tid;       // 64*64*64
  int x = idx & 63, y = (idx >> 6) & 63, b2 = idx >> 12;
  const float* sb = sim + (size_t)b2 * 16384;

  float patch[4][4];
#pragma unroll
  for (int r = 0; r < 4; r++) {
    int Y = 2 * y - 1 + r;
#pragma unroll
    for (int c = 0; c < 4; c++) {
      int X = 2 * x - 1 + c;
      patch[r][c] = (Y >= 0 && Y < 128 && X >= 0 && X < 128) ? sb[Y * 128 + X] : 0.f;
    }
  }

  _Float16 vout[32];
#pragma unroll
  for (int oc = 0; oc < 32; oc++) {
    float c00 = 0, c01 = 0, c10 = 0, c11 = 0;
#pragma unroll
    for (int tap = 0; tap < 9; tap++) {
      int dy = tap / 3, dx = tap - dy * 3;
      float w = w_s[oc * 9 + tap];
      c00 = fmaf(w, patch[dy][dx], c00);
      c01 = fmaf(w, patch[dy][dx + 1], c01);
      c10 = fmaf(w, patch[dy + 1][dx], c10);
      c11 = fmaf(w, patch[dy + 1][dx + 1], c11);
    }
    float v = fmaxf(fmaxf(c00, c01), fmaxf(c10, c11)) + b_s[oc];
    vout[oc] = (_Float16)fmaxf(v, 0.f);
  }
  _Float16* dst = x1 + (((size_t)b2 * 64 + y) * 64 + x) * 32;
#pragma unroll
  for (int q = 0; q < 4; q++)
    *(half8*)(dst + q * 8) = *(half8*)&vout[q * 8];
}

// ---------------------------------------------------------------------------
// Stage B2 (MFMA): conv2(3x3,32->64)+bias+relu+maxpool2, NHWC f16 in/out.
// ---------------------------------------------------------------------------
__global__ __launch_bounds__(256, 2) void conv2_mfma(
    const _Float16* __restrict__ x1, const _Float16* __restrict__ w2t,
    const float* __restrict__ bb, _Float16* __restrict__ x2)
{
  __shared__ _Float16 in_s[4 * 6 * 66 * 8];     // [k8][rr][px_mem][8]
  __shared__ _Float16 w_s[9 * 64 * 40];         // [tap][oc][ic(+pad)]
  __shared__ _Float16 pool_s[4][32 * 32];       // per wave [px][oc32]

  int b2 = blockIdx.y, ystrip = blockIdx.x;     // 16 strips x 4 conv rows
  int y0 = ystrip * 4;
  int tid = threadIdx.x;
  int w = tid >> 6, lane = tid & 63;
  int wyp = w >> 1, wn = w & 1;
  int lrow = lane & 15, lk8 = lane >> 4;

  {
    int px = tid >> 2, seg = tid & 3;
    const _Float16* base = x1 + ((size_t)b2 * 64) * 64 * 32;
    for (int rr = 0; rr < 6; rr++) {
      int yy = y0 - 1 + rr;
      half8 v = {};
      if (yy >= 0 && yy < 64) v = *(const half8*)(base + ((size_t)yy * 64 + px) * 32 + seg * 8);
      *(half8*)&in_s[((seg * 6 + rr) * 66 + px + 1) * 8] = v;
    }
    if (tid < 48) {
      int pr = tid >> 1, side = tid & 1;
      *(half8*)&in_s[(pr * 66 + side * 65) * 8] = (half8){};
    }
  }
  for (int e = tid; e < 2304; e += 256)
    *(half8*)&w_s[(e >> 2) * 40 + (e & 3) * 8] = *(const half8*)&w2t[e * 8];
  __syncthreads();

  f32x4 acc[2][4][2];
#pragma unroll
  for (int yr = 0; yr < 2; yr++)
#pragma unroll
    for (int xt = 0; xt < 4; xt++)
#pragma unroll
      for (int nt = 0; nt < 2; nt++)
        acc[yr][xt][nt] = (f32x4){0.f, 0.f, 0.f, 0.f};

#pragma unroll
  for (int tap = 0; tap < 9; tap++) {
    int dy = tap / 3, dx = tap - dy * 3;
    half8 bfr[2];
#pragma unroll
    for (int nt = 0; nt < 2; nt++)
      bfr[nt] = *(const half8*)&w_s[(tap * 64 + wn * 32 + nt * 16 + lrow) * 40 + lk8 * 8];
#pragma unroll
    for (int yr = 0; yr < 2; yr++) {
      int rr = 2 * wyp + yr + dy;
#pragma unroll
      for (int xt = 0; xt < 4; xt++) {
        half8 afr = *(const half8*)&in_s[((lk8 * 6 + rr) * 66 + xt * 16 + lrow + dx) * 8];
#pragma unroll
        for (int nt = 0; nt < 2; nt++)
          acc[yr][xt][nt] = __builtin_amdgcn_mfma_f32_16x16x32_f16(afr, bfr[nt], acc[yr][xt][nt], 0, 0, 0);
      }
    }
  }

  float bbv[2] = { bb[wn * 32 + lrow], bb[wn * 32 + 16 + lrow] };
#pragma unroll
  for (int nt = 0; nt < 2; nt++)
#pragma unroll
    for (int xt = 0; xt < 4; xt++)
#pragma unroll
      for (int pe = 0; pe < 2; pe++) {
        float m = fmaxf(fmaxf(acc[0][xt][nt][2 * pe], acc[0][xt][nt][2 * pe + 1]),
                        fmaxf(acc[1][xt][nt][2 * pe], acc[1][xt][nt][2 * pe + 1]));
        float v = fmaxf(m + bbv[nt], 0.f);
        int px = xt * 8 + lk8 * 2 + pe;
        pool_s[w][px * 32 + nt * 16 + lrow] = (_Float16)v;
      }
  __syncthreads();

  {
    int py = ystrip * 2 + wyp;
    int px = lane & 31, half = lane >> 5;
    const _Float16* srcp = &pool_s[w][px * 32 + half * 16];
    _Float16* dst = x2 + (((size_t)b2 * 32 + py) * 32 + px) * 64 + wn * 32 + half * 16;
    *(half8*)dst = *(const half8*)srcp;
    *(half8*)(dst + 8) = *(const half8*)(srcp + 8);
  }
}

// ---------------------------------------------------------------------------
// Stage B3 (MFMA): conv3(3x3,64->128)+bias+relu fused with convf(1x1)+bf.
// ---------------------------------------------------------------------------
__global__ __launch_bounds__(256, 2) void conv3_mfma(
    const _Float16* __restrict__ x2, const _Float16* __restrict__ w3t,
    const float* __restrict__ b3, const float* __restrict__ wf,
    const float* __restrict__ bf, float* __restrict__ shead)
{
  __shared__ _Float16 in_s[8 * 6 * 34 * 8];
  __shared__ _Float16 w_s[9 * 32 * 72];

  int b2 = blockIdx.y, ystrip = blockIdx.x;
  int y0 = ystrip * 4;
  int tid = threadIdx.x, w = tid >> 6, lane = tid & 63;
  int lrow = lane & 15, lk8 = lane >> 4;

  {
    int px = tid >> 3, seg = tid & 7;
    const _Float16* base = x2 + ((size_t)b2 * 32) * 32 * 64;
    for (int rr = 0; rr < 6; rr++) {
      int yy = y0 - 1 + rr;
      half8 v = {};
      if (yy >= 0 && yy < 32) v = *(const half8*)(base + ((size_t)yy * 32 + px) * 64 + seg * 8);
      *(half8*)&in_s[((seg * 6 + rr) * 34 + px + 1) * 8] = v;
    }
    if (tid < 96) {
      int pr = tid >> 1, side = tid & 1;
      *(half8*)&in_s[(pr * 34 + side * 33) * 8] = (half8){};
    }
  }

  f32x4 spart[2];
  spart[0] = (f32x4){0.f, 0.f, 0.f, 0.f};
  spart[1] = (f32x4){0.f, 0.f, 0.f, 0.f};
  int y = y0 + w;

  for (int og = 0; og < 4; og++) {
    __syncthreads();
    for (int e = tid; e < 2304; e += 256) {
      int s = e & 7, o = (e >> 3) & 31, tap = e >> 8;
      *(half8*)&w_s[(tap * 32 + o) * 72 + s * 8] =
          *(const half8*)&w3t[((size_t)(tap * 128 + og * 32 + o)) * 64 + s * 8];
    }
    __syncthreads();

    f32x4 acc[2][2];
#pragma unroll
    for (int mt = 0; mt < 2; mt++)
#pragma unroll
      for (int nt = 0; nt < 2; nt++)
        acc[mt][nt] = (f32x4){0.f, 0.f, 0.f, 0.f};

#pragma unroll
    for (int tap = 0; tap < 9; tap++) {
      int dy = tap / 3, dx = tap - dy * 3;
#pragma unroll
      for (int kc = 0; kc < 2; kc++) {
        half8 bfr[2];
#pragma unroll
        for (int nt = 0; nt < 2; nt++)
          bfr[nt] = *(const half8*)&w_s[(tap * 32 + nt * 16 + lrow) * 72 + kc * 32 + lk8 * 8];
#pragma unroll
        for (int mt = 0; mt < 2; mt++) {
          half8 afr = *(const half8*)&in_s[(((kc * 4 + lk8) * 6 + w + dy) * 34 + mt * 16 + lrow + dx) * 8];
#pragma unroll
          for (int nt = 0; nt < 2; nt++)
            acc[mt][nt] = __builtin_amdgcn_mfma_f32_16x16x32_f16(afr, bfr[nt], acc[mt][nt], 0, 0, 0);
        }
      }
    }

#pragma unroll
    for (int nt = 0; nt < 2; nt++) {
      int oc = og * 32 + nt * 16 + lrow;
      float b3v = b3[oc], wfv = wf[oc];
#pragma unroll
      for (int mt = 0; mt < 2; mt++)
#pragma unroll
        for (int e = 0; e < 4; e++)
          spart[mt][e] = fmaf(fmaxf(acc[mt][nt][e] + b3v, 0.f), wfv, spart[mt][e]);
    }
  }

#pragma unroll
  for (int mt = 0; mt < 2; mt++)
#pragma unroll
    for (int e = 0; e < 4; e++) {
      float v = spart[mt][e];
      v += __shfl_xor(v, 1); v += __shfl_xor(v, 2);
      v += __shfl_xor(v, 4); v += __shfl_xor(v, 8);
      spart[mt][e] = v;
    }
  if (lrow == 0) {
    float bfv = bf[0];
#pragma unroll
    for (int mt = 0; mt < 2; mt++)
#pragma unroll
      for (int e = 0; e < 4; e++) {
        int x = mt * 16 + lk8 * 4 + e;
        shead[(size_t)b2 * 1024 + y * 32 + x] = spart[mt][e] + bfv;
      }
  }
}

// ---------------------------------------------------------------------------
// Stage C: loss partials + clip + chamfer per b2.
// ---------------------------------------------------------------------------
__global__ __launch_bounds__(256) void head_final_kernel(
    const float* __restrict__ shead, const float* __restrict__ qm,
    const float* __restrict__ pm, const float* __restrict__ nm,
    float* __restrict__ out, float* __restrict__ loss_ws)
{
  int b2 = blockIdx.x, b = b2 & 31, g = b2 >> 5;
  const float* qmv = qm + b * 128;
  const float* tmv = (g ? nm : pm) + b * 128;

  __shared__ float mq4[32], mt4[32];
  __shared__ float red[256];
  __shared__ float rowv[32], rowm[32];

  int tid = threadIdx.x;
  if (tid < 32) {
    float a = qmv[tid * 4];
    a = fmaxf(a, qmv[tid * 4 + 1]); a = fmaxf(a, qmv[tid * 4 + 2]); a = fmaxf(a, qmv[tid * 4 + 3]);
    mq4[tid] = a;
    float c = tmv[tid * 4];
    c = fmaxf(c, tmv[tid * 4 + 1]); c = fmaxf(c, tmv[tid * 4 + 2]); c = fmaxf(c, tmv[tid * 4 + 3]);
    mt4[tid] = c;
  }
  __syncthreads();

  const float* s = shead + (size_t)b2 * 1024;
  float lp = 0.f;
#pragma unroll
  for (int r = 0; r < 4; r++) {
    float v = s[tid + 256 * r];
    lp += fmaxf(-1.f - v, 0.f) + fmaxf(v - 1.f, 0.f);
  }
  red[tid] = lp;
  __syncthreads();
  for (int off = 128; off; off >>= 1) {
    if (tid < off) red[tid] += red[tid + off];
    __syncthreads();
  }
  if (tid == 0) loss_ws[b2] = red[0];

  if (tid < 32) {
    int y = tid;
    float mqy = mq4[y];
    float rmax = -INFINITY, mm = 0.f;
    for (int x = 0; x < 32; x++) {
      float m = mqy * mt4[x];
      mm = fmaxf(mm, m);
      float v = s[y * 32 + x];
      v = fminf(fmaxf(v, -1.f), 1.f);
      rmax = fmaxf(rmax, m > 0.f ? v : -INFINITY);
    }
    rowv[y] = (mm > 0.f) ? rmax : 0.f;
    rowm[y] = mm;
  }
  __syncthreads();
  if (tid == 0) {
    float ss = 0.f, sm = 0.f;
    for (int y = 0; y < 32; y++) { ss += rowv[y]; sm += rowm[y]; }
    out[b2] = ss / sm;
  }
}

__global__ void loss_sum_kernel(const float* __restrict__ loss_ws, float* __restrict__ out)
{
  float v = loss_ws[threadIdx.x];
#pragma unroll
  for (int off = 32; off >= 1; off >>= 1) v += __shfl_down(v, off);
  if (threadIdx.x == 0) out[64] = v;
}

// ---------------------------------------------------------------------------
extern "C" void kernel_launch(void* const* d_in, const int* in_sizes, int n_in,
                              void* d_out, int out_size, void* d_ws, size_t ws_size,
                              hipStream_t stream)
{
  (void)in_sizes; (void)n_in; (void)out_size; (void)ws_size;
  const float* A   = (const float*)d_in[0];
  const float* P   = (const float*)d_in[1];
  const float* Nn  = (const float*)d_in[2];
  const float* qm  = (const float*)d_in[3];
  const float* pm  = (const float*)d_in[4];
  const float* nm  = (const float*)d_in[5];
  const float* w1  = (const float*)d_in[6];
  const float* b1  = (const float*)d_in[7];
  const float* w2  = (const float*)d_in[8];
  const float* b2w = (const float*)d_in[9];
  const float* w3  = (const float*)d_in[10];
  const float* b3  = (const float*)d_in[11];
  const float* wf  = (const float*)d_in[12];
  const float* bf  = (const float*)d_in[13];
  float* out = (float*)d_out;

  const size_t F16SZ = (size_t)BTRD * 32 * sizeof(_Float16);  // 37,748,736 B
  char* ws = (char*)d_ws;
  _Float16* Qf = (_Float16*)(ws);
  _Float16* Pf = (_Float16*)(ws + F16SZ);
  _Float16* Nf = (_Float16*)(ws + 2 * F16SZ);
  char* ws2 = ws + 3 * F16SZ;
  float*     sim   = (float*)(ws2);                               // 4 MB
  _Float16*  x1    = (_Float16*)(ws2 + (4u << 20));               // 16 MB NHWC
  _Float16*  x2    = (_Float16*)(ws2 + (20u << 20));              // 8 MB NHWC
  float*     shead = (float*)(ws2 + (28u << 20));                 // 256 KB
  _Float16*  w2t   = (_Float16*)(ws2 + (29u << 20));              // 36 KB
  _Float16*  w3t   = (_Float16*)(ws2 + (29u << 20) + (256u << 10)); // 144 KB
  float*     lws   = (float*)(ws2 + (30u << 20));

  prep_kernel<<<28008, 256, 0, stream>>>(A, P, Nn, Qf, Pf, Nf, w2, w3, w2t, w3t);

  sim_mfma_kernel<<<512, 256, 0, stream>>>(Qf, Pf, Nf, qm, pm, nm, sim);
  conv1_kernel<<<1024, 256, 0, stream>>>(sim, w1, b1, x1);
  conv2_mfma<<<dim3(16, 64), 256, 0, stream>>>(x1, w2t, b2w, x2);
  conv3_mfma<<<dim3(8, 64), 256, 0, stream>>>(x2, w3t, b3, wf, bf, shead);
  head_final_kernel<<<64, 256, 0, stream>>>(shead, qm, pm, nm, out, lws);
  loss_sum_kernel<<<1, 64, 0, stream>>>(lws, out);
}